// Round 13
// baseline (880.506 us; speedup 1.0000x reference)
//
#include <hip/hip_runtime.h>
#include <hip/hip_bf16.h>
#include <float.h>
#include <math.h>

typedef __hip_bfloat16 bf16;
typedef unsigned long long u64;

#define BATCH 32
#define NPTS  1024
#define KNN   20
#define NB    (BATCH*NPTS)      // 32768 nodes
#define NEDGE (NB*KNN)          // 655360 edges

// ---- workspace layout (float units), ws_size-adaptive ----
#define OFF_FLAG 512u
#define OFF_INB  1024u
#define OFF_IDX  988928u          // 655360 ints (idx1 early, idx2 late; s1/s2 after x2)
#define OFF_X1   1644288u         // NB*64
#define OFF_X2   3741440u         // NB*128 ; a1 @ OFF_X2, c1 @ OFF_C1 (early)
#define OFF_C1   5838592u
#define OFF_POOL 7935744u         // pool4: 4 x 32*1024
#define SLOW_END 8066816u         // 32.3 MB
#define OFF_B2H  8066816u         // NB*64 (fast path only)
#define FAST_END 10163968u        // 40.7 MB
// kNN phase-A value lists (u32, 32768x2x20 = 5.2MB) + kthr (u32[32768]) alias
// OFF_X2 (dead there at both kNN points). Head acts s1/s2 alias OFF_IDX.
// ---- layout inside inb (canonical fp32 inputs) ----
#define IN_POSF 0u
#define IN_B1   98304u
#define IN_G1   98368u
#define IN_BE1  98432u
#define IN_B2   98496u
#define IN_G2   98560u
#define IN_BE2  98624u
#define IN_B3   98688u
#define IN_BC2  98752u
#define IN_BL   98880u
#define IN_BM1  99904u
#define IN_BM2  100416u
#define IN_BM3  100672u
#define IN_W1   100736u
#define IN_WBUF 101120u
#define WB_W2   0u
#define WB_W3   4096u
#define WB_WD   8192u            // Wc2 top-bot diff [64x128]
#define WB_WBOT 16384u           // Wc2 bottom      [64x128]
#define WB_WL   24576u
#define WB_WM1  221184u          // stored TRANSPOSED [512][1024] (head wave-dots)
#define WB_WM2  745472u          // stored TRANSPOSED [256][512]
#define WB_WM3  876544u          // stored TRANSPOSED [40][256]
#define IN_TOTAL 987904u

__device__ __forceinline__ float bf2f(bf16 v){ return __bfloat162float(v); }

// monotone float->u32 map: preserves IEEE-754 total order for all finite values
__device__ __forceinline__ unsigned int mono32(float f){
  unsigned int b = __float_as_uint(f);
  return b ^ ((unsigned int)((int)b >> 31) | 0x80000000u);
}

// ======== MFMA machinery (bf16 hi/lo split, fp32-accurate) ========
typedef __attribute__((ext_vector_type(8))) short bf16x8;
typedef __attribute__((ext_vector_type(4))) float f32x4;

__device__ __forceinline__ unsigned short bfhi(float f){
  unsigned int u = __float_as_uint(f);
  u += 0x7FFFu + ((u >> 16) & 1u);      // RNE to bf16
  return (unsigned short)(u >> 16);
}
__device__ __forceinline__ void bfsplit(float f, unsigned short& h, unsigned short& l){
  h = bfhi(f);
  float fh = __uint_as_float(((unsigned int)h) << 16);
  l = bfhi(f - fh);
}

// ======== top-20 VALUES via u32 keys + min/max sorted-insert ========
// Round-12 lesson: phase A/B "bit-identical recompute" across SEPARATE kernels
// is NOT guaranteed (ffp-contract decisions differ per call site) -> strict
// ==/< threshold tests misclassified near-threshold candidates (absmax 4.6e-2).
// Robust scheme: phase A gives approximate-exact threshold kthr; phase B
// collects ALL candidates within kthr + 2048 ulps (margin >> contraction
// drift, << 20th-21st neighbor gap) WITH their (key, idx), then does an exact
// lexicographic (d_B, idx) top-20 selection over the <=32 collected entries.
// Output = exact top-k under the self-consistent phase-B metric.
#define REP20(M) M(0) M(1) M(2) M(3) M(4) M(5) M(6) M(7) M(8) M(9) \
                 M(10) M(11) M(12) M(13) M(14) M(15) M(16) M(17) M(18) M(19)
#define SH19(M) M(19,18) M(18,17) M(17,16) M(16,15) M(15,14) M(14,13) M(13,12) \
                M(12,11) M(11,10) M(10,9) M(9,8) M(8,7) M(7,6) M(6,5) M(5,4) \
                M(4,3) M(3,2) M(2,1) M(1,0)

__device__ __forceinline__ unsigned umin_(unsigned a, unsigned b){ return a<b?a:b; }
__device__ __forceinline__ unsigned umax_(unsigned a, unsigned b){ return a>b?a:b; }

#define KDECLU(p) unsigned uk##p = 0xFFFFFFFFu;
#define KMMU(p,pm) uk##p = umin_(uk##p, umax_(uk##pm, _k));
#define INS_U32(kv) do{ unsigned _k=(kv); SH19(KMMU) uk0 = umin_(uk0, _k); }while(0)
#define KPUBU_A(p) mrgA[q_l*21+p] = uk##p;
#define KPUBU_B(p) mrgB[q_l*21+p] = uk##p;
#define KSTGU(p)   gpart[p] = uk##p;
#define KLDAU(p)   unsigned uk##p = pa[p];

// shared distance helpers (same source for A/B; margin covers any drift)
__device__ __forceinline__ float pdist3(float xi0, float xi1, float xi2, float sqi,
                                        float px, float py, float pz, float sq){
  float dot = xi0*px + xi1*py + xi2*pz;
  return sqi + sq - 2.0f*dot;
}
__device__ __forceinline__ float qdist(float sq_q, float sq_c,
                                       float p0, float p1, float p2){
  return sq_q + sq_c - 2.0f*(p0 + p1 + p2);
}

// exact top-20 selection by (key, idx) over n<=32 LDS entries; writes 20 idx.
__device__ __forceinline__ void sel20(unsigned* keyr, int* idxr, int n, int* optr){
  for (int s = 0; s < 20; s++){
    unsigned bk = 0xFFFFFFFFu; int bi = 0x7FFFFFFF; int bm = 0;
    for (int t = 0; t < n; t++){
      unsigned k = keyr[t]; int id = idxr[t];
      bool better = (k < bk) || (k == bk && id < bi);
      bk = better ? k : bk; bi = better ? id : bi; bm = better ? t : bm;
    }
    optr[s] = (bi == 0x7FFFFFFF) ? 0 : bi;
    keyr[bm] = 0xFFFFFFFFu; idxr[bm] = 0x7FFFFFFF;
  }
}

// ---------------- dtype sniff (fp32 vs bf16 inputs) ----------------
__global__ void k_sniff(const void* pos_raw, int* flag){
  if (blockIdx.x == 0 && threadIdx.x == 0){
    const unsigned short* h = (const unsigned short*)pos_raw;
    int wild = 0;
    for (int k = 0; k < 16; k++){
      unsigned int bits = ((unsigned int)h[2*k]) << 16;
      float v = __uint_as_float(bits);
      float a = fabsf(v);
      if (a != 0.0f && (v != v || a > 1e10f || a < 1e-10f)) wild++;
    }
    *flag = (wild >= 4) ? 1 : 0;
  }
}

__device__ __forceinline__ float rdv(const void* p, int i, int f){
  return f ? ((const float*)p)[i] : bf2f(((const bf16*)p)[i]);
}

// ---------------- normalize ALL inputs to canonical fp32 buffer ----------------
__global__ __launch_bounds__(256) void k_cvt(
    const void* pos, const void* W1, const void* b1, const void* g1, const void* be1,
    const void* W2, const void* b2, const void* g2, const void* be2,
    const void* W3, const void* b3, const void* Wc2, const void* bc2,
    const void* Wl, const void* bl, const void* Wm1, const void* bm1,
    const void* Wm2, const void* bm2, const void* Wm3, const void* bm3,
    const int* flag, float* inb){
  int id = blockIdx.x*256 + threadIdx.x;
  if (id >= (int)IN_TOTAL) return;
  int f = *flag;
  float v;
  if      (id < 98304)  v = rdv(pos, id, f);
  else if (id < 98368)  v = rdv(b1,  id-98304, f);
  else if (id < 98432)  v = rdv(g1,  id-98368, f);
  else if (id < 98496)  v = rdv(be1, id-98432, f);
  else if (id < 98560)  v = rdv(b2,  id-98496, f);
  else if (id < 98624)  v = rdv(g2,  id-98560, f);
  else if (id < 98688)  v = rdv(be2, id-98624, f);
  else if (id < 98752)  v = rdv(b3,  id-98688, f);
  else if (id < 98880)  v = rdv(bc2, id-98752, f);
  else if (id < 99904)  v = rdv(bl,  id-98880, f);
  else if (id < 100416) v = rdv(bm1, id-99904, f);
  else if (id < 100672) v = rdv(bm2, id-100416, f);
  else if (id < 100712) v = rdv(bm3, id-100672, f);
  else if (id < 100736) v = 0.0f;
  else if (id < 101120) v = rdv(W1,  id-100736, f);
  else {
    int t = id - 101120;
    if      (t < 4096)   v = rdv(W2, t, f);
    else if (t < 8192)   v = rdv(W3, t-4096, f);
    else if (t < 16384){ int u = t-8192;  v = rdv(Wc2, u, f) - rdv(Wc2, 8192+u, f); }
    else if (t < 24576){ int u = t-16384; v = rdv(Wc2, 8192+u, f); }
    else if (t < 221184) v = rdv(Wl,  t-24576, f);
    else if (t < 745472){ int u = t-221184; int c = u>>10, d = u&1023; v = rdv(Wm1, d*512+c, f); }
    else if (t < 876544){ int u = t-745472; int c = u>>9,  d = u&511;  v = rdv(Wm2, d*256+c, f); }
    else               { int u = t-876544; int c = u>>8,  d = u&255;  v = rdv(Wm3, d*40+c, f); }
  }
  inb[id] = v;
}

// ---------------- a1/c1: affine decomposition of EdgeConv1 layer1 ----------------
__global__ __launch_bounds__(256) void k_prep1(const float* inb, float* a1, float* c1){
  const float* posf = inb + IN_POSF;
  const float* W1f  = inb + IN_W1;
  const float* b1f  = inb + IN_B1;
  int id = blockIdx.x*256 + threadIdx.x;
  int bn = id >> 6, c = id & 63;
  float p0 = posf[bn*3], p1 = posf[bn*3+1], p2 = posf[bn*3+2];
  float wt0 = W1f[c],     wt1 = W1f[64+c],  wt2 = W1f[128+c];
  float wb0 = W1f[192+c], wb1 = W1f[256+c], wb2 = W1f[320+c];
  float cv = p0*wb0 + p1*wb1 + p2*wb2;
  float av = p0*(wt0-wb0) + p1*(wt1-wb1) + p2*(wt2-wb2) + b1f[c];
  a1[id] = av;  c1[id] = cv;
}

// ---------------- kNN1 phase A: top-20 distance VALUES per half (u32) ----------------
__global__ __launch_bounds__(256, 2) void k_knn1a(const float* inb, unsigned* part){
  const float* posf = inb + IN_POSF;
  __shared__ __align__(16) char sm1[16384];
  float* psx = (float*)sm1;
  float* psy = psx + 1024;
  float* psz = psy + 1024;
  float* sqs = psz + 1024;
  unsigned* mrgA = (unsigned*)sm1;          // overlay (post-scan only)
  unsigned* mrgB = (unsigned*)(sm1 + 5376);
  int bb   = blockIdx.x >> 5;
  int qg   = (blockIdx.x >> 1) & 15;
  int half = blockIdx.x & 1;
  int tid = threadIdx.x;
  int q_l = tid & 63;
  int slot = tid >> 6;
  for (int t = tid; t < 1024; t += 256){
    float x = posf[(bb*1024+t)*3], y = posf[(bb*1024+t)*3+1], z = posf[(bb*1024+t)*3+2];
    psx[t] = x; psy[t] = y; psz[t] = z; sqs[t] = x*x + y*y + z*z;
  }
  __syncthreads();
  int i_l = qg*64 + q_l;
  float xi0 = psx[i_l], xi1 = psy[i_l], xi2 = psz[i_l];
  float sqi = sqs[i_l];
  REP20(KDECLU)
  int cbase = half*512;
  for (int u = 0; u < 128; u++){
    int jj = cbase + 4*u + slot;
    float d = pdist3(xi0, xi1, xi2, sqi, psx[jj], psy[jj], psz[jj], sqs[jj]);
    INS_U32(mono32(d));
  }
  __syncthreads();                    // scan arrays dead from here (union!)
  if (slot == 1){ REP20(KPUBU_A) }
  if (slot == 3){ REP20(KPUBU_B) }
  __syncthreads();
  if ((slot & 1) == 0){
    const unsigned* src = (slot == 0) ? &mrgA[q_l*21] : &mrgB[q_l*21];
    for (int p = 0; p < KNN; p++){
      unsigned kv = src[p];
      if (kv > uk19) break;           // sorted source: rest are worse
      INS_U32(kv);
    }
  }
  __syncthreads();
  if (slot == 2){ REP20(KPUBU_B) }
  __syncthreads();
  if (slot == 0){
    const unsigned* src = &mrgB[q_l*21];
    for (int p = 0; p < KNN; p++){
      unsigned kv = src[p];
      if (kv > uk19) break;
      INS_U32(kv);
    }
    int gi = bb*1024 + i_l;
    unsigned* gpart = part + (size_t)(gi*2 + half)*KNN;
    REP20(KSTGU)
  }
}

// ---------------- merge half value-lists -> per-query 20th value kthr ----------------
__global__ __launch_bounds__(256) void k_mrg2(const unsigned* part, unsigned* kthr){
  int gi = blockIdx.x*256 + threadIdx.x;    // grid 128 -> 32768 queries
  const unsigned* pa = part + (size_t)gi*2*KNN;
  REP20(KLDAU)                               // init from half-0 list (sorted)
  for (int p = 0; p < KNN; p++){
    unsigned kv = pa[KNN + p];
    if (kv > uk19) break;                    // sorted source: rest are worse
    INS_U32(kv);
  }
  kthr[gi] = uk19;
}

// ---------------- kNN1 phase B: margin-collect (key,idx) + exact sel20 ----------------
__global__ __launch_bounds__(256) void k_knn1b(const float* inb, const unsigned* kthr,
                                               int* idx1){
  const float* posf = inb + IN_POSF;
  __shared__ float psx[1024], psy[1024], psz[1024], sqs[1024];
  __shared__ unsigned cnt[64];
  __shared__ unsigned keyl[64][33];          // padded: avoid stride-32 banks
  __shared__ int      idxl[64][33];
  int bb = blockIdx.x >> 4, qg = blockIdx.x & 15;
  int tid = threadIdx.x;
  for (int t = tid; t < 1024; t += 256){
    float x = posf[(bb*1024+t)*3], y = posf[(bb*1024+t)*3+1], z = posf[(bb*1024+t)*3+2];
    psx[t] = x; psy[t] = y; psz[t] = z; sqs[t] = x*x + y*y + z*z;
  }
  if (tid < 64) cnt[tid] = 0u;
  __syncthreads();
  int q_l = tid & 63, slot = tid >> 6;
  int i_l = qg*64 + q_l;
  float xi0 = psx[i_l], xi1 = psy[i_l], xi2 = psz[i_l];
  float sqi = sqs[i_l];
  unsigned kt = kthr[bb*1024 + i_l];
  unsigned ktin = kt + 2048u; if (ktin < kt) ktin = 0xFFFFFFFFu;   // margin
  for (int u = 0; u < 256; u++){
    int jj = 4*u + slot;
    float d = pdist3(xi0, xi1, xi2, sqi, psx[jj], psy[jj], psz[jj], sqs[jj]);
    unsigned k = mono32(d);
    if (k <= ktin){
      unsigned p = atomicAdd(&cnt[q_l], 1u);
      if (p < 32u){ keyl[q_l][p] = k; idxl[q_l][p] = jj; }
    }
  }
  __syncthreads();
  if (tid < 64){
    int n = (int)umin_(cnt[tid], 32u);
    int* optr = idx1 + (size_t)(bb*1024 + qg*64 + tid)*KNN;
    sel20(&keyl[tid][0], &idxl[tid][0], n, optr);
  }
}

// ---------------- BN1 stats ----------------
__global__ __launch_bounds__(256) void k_stats1(const float* a1, const float* c1,
                                                const int* idx1, double* stats){
  __shared__ float rs[256], rs2[256];
  int tid = threadIdx.x, c = tid & 63, slot = tid >> 6;
  int base = blockIdx.x * 1024;
  float s = 0.f, s2 = 0.f;
  for (int t = 0; t < 256; t++){
    unsigned e = (unsigned)(base + t*4 + slot);
    int i = (int)(e / 20u);
    int b = i >> 10;
    int j = idx1[e];
    float h = a1[i*64+c] + c1[((b<<10)+j)*64 + c];
    s += h; s2 += h*h;
  }
  rs[tid] = s; rs2[tid] = s2;
  __syncthreads();
  if (slot == 0){
    double ts  = (double)rs[c]  + (double)rs[64+c]  + (double)rs[128+c]  + (double)rs[192+c];
    double ts2 = (double)rs2[c] + (double)rs2[64+c] + (double)rs2[128+c] + (double)rs2[192+c];
    atomicAdd(&stats[c], ts);
    atomicAdd(&stats[64+c], ts2);
  }
}

// ================= MFMA edge-MLP (packed edges, zero padding) =================

// ---------------- BN2 stats over P = H1 @ W2 (raw, no b2) ----------------
__global__ __launch_bounds__(256) void k_stats2m(const float* a1, const float* c1,
    const int* idx1, const float* inb, double* stats){
  __shared__ __align__(16) unsigned short W2hF[4096], W2lF[4096];
  __shared__ float sc1s[64], sh1s[64];
  __shared__ float rs[4][64], rs2[4][64];
  int tid = threadIdx.x;
  const float* wbuf = inb + IN_WBUF;
  for (int t = tid; t < 4096; t += 256){
    int nt = t >> 10, ks = (t >> 9) & 1, ln = (t >> 3) & 63, e = t & 7;
    int row = ks*32 + (ln >> 4)*8 + e;
    int col = nt*16 + (ln & 15);
    unsigned short hh, ll;
    bfsplit(wbuf[WB_W2 + row*64 + col], hh, ll);
    W2hF[t] = hh; W2lF[t] = ll;
  }
  if (tid < 64){
    int c = tid;
    const double M = (double)NEDGE;
    double m1 = stats[c]/M;
    double v1 = stats[64+c]/M - m1*m1;
    double r1 = 1.0/sqrt(v1 + 1e-5);
    double g1 = (double)inb[IN_G1 + c];
    sc1s[c] = (float)(g1*r1);
    sh1s[c] = (float)((double)inb[IN_BE1 + c] - m1*g1*r1);
  }
  __syncthreads();
  int lane = tid & 63, wv = tid >> 6;
  int c16 = lane & 15, ag = lane >> 4, kb0 = ag*8;
  float sa[4] = {0,0,0,0}, qa[4] = {0,0,0,0};
  for (int rd = 0; rd < 3; rd++){
    int T = rd*4 + wv;
    if (T < 10){
      int krow = 16*T + c16;                       // block-local edge 0..159
      int node = (krow*52429) >> 20;               // krow/20
      int nodeg = blockIdx.x*8 + node;
      int j = idx1[blockIdx.x*160 + krow];         // coalesced
      int gj = ((nodeg >> 10) << 10) + j;
      const float* ar = a1 + (size_t)nodeg*64;
      const float* cr = c1 + (size_t)gj*64;
      f32x4 av0 = *(const f32x4*)(ar + kb0);
      f32x4 av1 = *(const f32x4*)(ar + kb0 + 4);
      f32x4 av2 = *(const f32x4*)(ar + 32 + kb0);
      f32x4 av3 = *(const f32x4*)(ar + 36 + kb0);
      f32x4 cv0 = *(const f32x4*)(cr + kb0);
      f32x4 cv1 = *(const f32x4*)(cr + kb0 + 4);
      f32x4 cv2 = *(const f32x4*)(cr + 32 + kb0);
      f32x4 cv3 = *(const f32x4*)(cr + 36 + kb0);
      bf16x8 a0h, a0l, a1h_, a1l_;
      #pragma unroll
      for (int e = 0; e < 4; e++){
        unsigned short hh, ll;
        float h;
        h = fmaxf((av0[e]+cv0[e])*sc1s[kb0+e] + sh1s[kb0+e], 0.f);
        bfsplit(h, hh, ll); a0h[e] = (short)hh; a0l[e] = (short)ll;
        h = fmaxf((av1[e]+cv1[e])*sc1s[kb0+4+e] + sh1s[kb0+4+e], 0.f);
        bfsplit(h, hh, ll); a0h[4+e] = (short)hh; a0l[4+e] = (short)ll;
        h = fmaxf((av2[e]+cv2[e])*sc1s[32+kb0+e] + sh1s[32+kb0+e], 0.f);
        bfsplit(h, hh, ll); a1h_[e] = (short)hh; a1l_[e] = (short)ll;
        h = fmaxf((av3[e]+cv3[e])*sc1s[36+kb0+e] + sh1s[36+kb0+e], 0.f);
        bfsplit(h, hh, ll); a1h_[4+e] = (short)hh; a1l_[4+e] = (short)ll;
      }
      #pragma unroll
      for (int nt = 0; nt < 4; nt++){
        bf16x8 wh0 = *(const bf16x8*)(W2hF + (nt*2+0)*512 + lane*8);
        bf16x8 wh1 = *(const bf16x8*)(W2hF + (nt*2+1)*512 + lane*8);
        bf16x8 wl0 = *(const bf16x8*)(W2lF + (nt*2+0)*512 + lane*8);
        bf16x8 wl1 = *(const bf16x8*)(W2lF + (nt*2+1)*512 + lane*8);
        f32x4 acc = {0.f, 0.f, 0.f, 0.f};
        acc = __builtin_amdgcn_mfma_f32_16x16x32_bf16(a0h,  wh0, acc, 0, 0, 0);
        acc = __builtin_amdgcn_mfma_f32_16x16x32_bf16(a1h_, wh1, acc, 0, 0, 0);
        acc = __builtin_amdgcn_mfma_f32_16x16x32_bf16(a0h,  wl0, acc, 0, 0, 0);
        acc = __builtin_amdgcn_mfma_f32_16x16x32_bf16(a1h_, wl1, acc, 0, 0, 0);
        acc = __builtin_amdgcn_mfma_f32_16x16x32_bf16(a0l,  wh0, acc, 0, 0, 0);
        acc = __builtin_amdgcn_mfma_f32_16x16x32_bf16(a1l_, wh1, acc, 0, 0, 0);
        #pragma unroll
        for (int r = 0; r < 4; r++){
          float v = acc[r];                        // all rows real (no padding)
          sa[nt] += v; qa[nt] += v*v;
        }
      }
    }
  }
  #pragma unroll
  for (int nt = 0; nt < 4; nt++){
    sa[nt] += __shfl_xor(sa[nt], 16); sa[nt] += __shfl_xor(sa[nt], 32);
    qa[nt] += __shfl_xor(qa[nt], 16); qa[nt] += __shfl_xor(qa[nt], 32);
  }
  if (ag == 0){
    #pragma unroll
    for (int nt = 0; nt < 4; nt++){
      rs[wv][nt*16+c16] = sa[nt];
      rs2[wv][nt*16+c16] = qa[nt];
    }
  }
  __syncthreads();
  if (tid < 64){
    double ts = (double)rs[0][tid] + (double)rs[1][tid]
              + (double)rs[2][tid] + (double)rs[3][tid];
    double tq = (double)rs2[0][tid] + (double)rs2[1][tid]
              + (double)rs2[2][tid] + (double)rs2[3][tid];
    atomicAdd(&stats[128+tid], ts);
    atomicAdd(&stats[192+tid], tq);
  }
}

// ---------------- full MLP1 via MFMA + max over k -> x1 (packed edges) ----------------
__global__ __launch_bounds__(256, 2) void k_x1m(const float* a1, const float* c1,
    const int* idx1, const float* inb, const double* stats, float* x1){
  __shared__ __align__(16) unsigned short W2hF[4096], W2lF[4096];   // 8KB each
  __shared__ __align__(16) unsigned short W3hF[4096], W3lF[4096];
  __shared__ __align__(16) float scr[4][16*68];     // per-wave H2 relayout scratch
  __shared__ unsigned int mxp2[8][64];              // per-node channel maxes (mono32)
  __shared__ float sc1s[64], sh1s[64], sc2s[64], sh2s[64];
  int tid = threadIdx.x;
  const float* wbuf = inb + IN_WBUF;
  for (int t = tid; t < 4096; t += 256){
    int nt = t >> 10, ks = (t >> 9) & 1, ln = (t >> 3) & 63, e = t & 7;
    int row = ks*32 + (ln >> 4)*8 + e;
    int col = nt*16 + (ln & 15);
    unsigned short hh, ll;
    bfsplit(wbuf[WB_W2 + row*64 + col], hh, ll);
    W2hF[t] = hh; W2lF[t] = ll;
    bfsplit(wbuf[WB_W3 + row*64 + col], hh, ll);
    W3hF[t] = hh; W3lF[t] = ll;
  }
  for (int t = tid; t < 512; t += 256) ((unsigned int*)mxp2)[t] = 0u;
  if (tid < 64){
    int c = tid;
    const double M = (double)NEDGE;
    double m1 = stats[c]/M;
    double v1 = stats[64+c]/M - m1*m1;
    double r1 = 1.0/sqrt(v1 + 1e-5);
    double g1 = (double)inb[IN_G1 + c];
    sc1s[c] = (float)(g1*r1);
    sh1s[c] = (float)((double)inb[IN_BE1 + c] - m1*g1*r1);
    double mp = stats[128+c]/M;                  // mean of raw P (b2 cancels in BN)
    double v2 = stats[192+c]/M - mp*mp;
    double r2 = 1.0/sqrt(v2 + 1e-5);
    double g2 = (double)inb[IN_G2 + c];
    sc2s[c] = (float)(g2*r2);
    sh2s[c] = (float)((double)inb[IN_BE2 + c] - mp*g2*r2);
  }
  __syncthreads();
  int lane = tid & 63, wv = tid >> 6;
  int c16 = lane & 15, ag = lane >> 4, kb0 = ag*8;
  float scn[4], shn[4];
  #pragma unroll
  for (int nt = 0; nt < 4; nt++){
    scn[nt] = sc2s[nt*16 + c16];
    shn[nt] = sh2s[nt*16 + c16];
  }
  float* sw = &scr[wv][0];
  for (int rd = 0; rd < 3; rd++){
    int T = rd*4 + wv;
    if (T < 10){
      int krow = 16*T + c16;                       // block-local edge 0..159
      int node = (krow*52429) >> 20;               // krow/20
      int nodeg = blockIdx.x*8 + node;
      int j = idx1[blockIdx.x*160 + krow];         // coalesced
      int gj = ((nodeg >> 10) << 10) + j;
      const float* ar = a1 + (size_t)nodeg*64;
      const float* cr = c1 + (size_t)gj*64;
      f32x4 av0 = *(const f32x4*)(ar + kb0);
      f32x4 av1 = *(const f32x4*)(ar + kb0 + 4);
      f32x4 av2 = *(const f32x4*)(ar + 32 + kb0);
      f32x4 av3 = *(const f32x4*)(ar + 36 + kb0);
      f32x4 cv0 = *(const f32x4*)(cr + kb0);
      f32x4 cv1 = *(const f32x4*)(cr + kb0 + 4);
      f32x4 cv2 = *(const f32x4*)(cr + 32 + kb0);
      f32x4 cv3 = *(const f32x4*)(cr + 36 + kb0);
      bf16x8 a0h, a0l, a1h_, a1l_;
      #pragma unroll
      for (int e = 0; e < 4; e++){
        unsigned short hh, ll;
        float h;
        h = fmaxf((av0[e]+cv0[e])*sc1s[kb0+e] + sh1s[kb0+e], 0.f);
        bfsplit(h, hh, ll); a0h[e] = (short)hh; a0l[e] = (short)ll;
        h = fmaxf((av1[e]+cv1[e])*sc1s[kb0+4+e] + sh1s[kb0+4+e], 0.f);
        bfsplit(h, hh, ll); a0h[4+e] = (short)hh; a0l[4+e] = (short)ll;
        h = fmaxf((av2[e]+cv2[e])*sc1s[32+kb0+e] + sh1s[32+kb0+e], 0.f);
        bfsplit(h, hh, ll); a1h_[e] = (short)hh; a1l_[e] = (short)ll;
        h = fmaxf((av3[e]+cv3[e])*sc1s[36+kb0+e] + sh1s[36+kb0+e], 0.f);
        bfsplit(h, hh, ll); a1h_[4+e] = (short)hh; a1l_[4+e] = (short)ll;
      }
      // ---- GEMM1: P = H1 @ W2 (B-fragments streamed from LDS) ----
      f32x4 pacc[4];
      #pragma unroll
      for (int nt = 0; nt < 4; nt++){
        bf16x8 wh0 = *(const bf16x8*)(W2hF + (nt*2+0)*512 + lane*8);
        bf16x8 wh1 = *(const bf16x8*)(W2hF + (nt*2+1)*512 + lane*8);
        bf16x8 wl0 = *(const bf16x8*)(W2lF + (nt*2+0)*512 + lane*8);
        bf16x8 wl1 = *(const bf16x8*)(W2lF + (nt*2+1)*512 + lane*8);
        f32x4 acc = {0.f, 0.f, 0.f, 0.f};
        acc = __builtin_amdgcn_mfma_f32_16x16x32_bf16(a0h,  wh0, acc, 0, 0, 0);
        acc = __builtin_amdgcn_mfma_f32_16x16x32_bf16(a1h_, wh1, acc, 0, 0, 0);
        acc = __builtin_amdgcn_mfma_f32_16x16x32_bf16(a0h,  wl0, acc, 0, 0, 0);
        acc = __builtin_amdgcn_mfma_f32_16x16x32_bf16(a1h_, wl1, acc, 0, 0, 0);
        acc = __builtin_amdgcn_mfma_f32_16x16x32_bf16(a0l,  wh0, acc, 0, 0, 0);
        acc = __builtin_amdgcn_mfma_f32_16x16x32_bf16(a1l_, wh1, acc, 0, 0, 0);
        pacc[nt] = acc;
      }
      // ---- BN2 + relu, relayout D->A via per-wave LDS scratch ----
      #pragma unroll
      for (int nt = 0; nt < 4; nt++){
        #pragma unroll
        for (int r = 0; r < 4; r++){
          float v = fmaxf(pacc[nt][r]*scn[nt] + shn[nt], 0.f);
          sw[(4*ag + r)*68 + nt*16 + c16] = v;
        }
      }
      f32x4 h20 = *(const f32x4*)(sw + c16*68 + kb0);
      f32x4 h21 = *(const f32x4*)(sw + c16*68 + kb0 + 4);
      f32x4 h22 = *(const f32x4*)(sw + c16*68 + 32 + kb0);
      f32x4 h23 = *(const f32x4*)(sw + c16*68 + 36 + kb0);
      bf16x8 b0h, b0l, b1h, b1l;
      #pragma unroll
      for (int e = 0; e < 4; e++){
        unsigned short hh, ll;
        bfsplit(h20[e], hh, ll); b0h[e] = (short)hh; b0l[e] = (short)ll;
        bfsplit(h21[e], hh, ll); b0h[4+e] = (short)hh; b0l[4+e] = (short)ll;
        bfsplit(h22[e], hh, ll); b1h[e] = (short)hh; b1l[e] = (short)ll;
        bfsplit(h23[e], hh, ll); b1h[4+e] = (short)hh; b1l[4+e] = (short)ll;
      }
      // ---- GEMM2 + boundary-split masked max into per-node LDS slots ----
      int rowA = 16*T;
      int nA = (rowA*52429) >> 20;                 // first node of tile (local)
      int bnd = nA*20 + 20 - rowA;                 // rows < bnd -> node nA
      int hasB = (bnd < 16);
      #pragma unroll
      for (int nt = 0; nt < 4; nt++){
        bf16x8 wh0 = *(const bf16x8*)(W3hF + (nt*2+0)*512 + lane*8);
        bf16x8 wh1 = *(const bf16x8*)(W3hF + (nt*2+1)*512 + lane*8);
        bf16x8 wl0 = *(const bf16x8*)(W3lF + (nt*2+0)*512 + lane*8);
        bf16x8 wl1 = *(const bf16x8*)(W3lF + (nt*2+1)*512 + lane*8);
        f32x4 acc = {0.f, 0.f, 0.f, 0.f};
        acc = __builtin_amdgcn_mfma_f32_16x16x32_bf16(b0h, wh0, acc, 0, 0, 0);
        acc = __builtin_amdgcn_mfma_f32_16x16x32_bf16(b1h, wh1, acc, 0, 0, 0);
        acc = __builtin_amdgcn_mfma_f32_16x16x32_bf16(b0h, wl0, acc, 0, 0, 0);
        acc = __builtin_amdgcn_mfma_f32_16x16x32_bf16(b1h, wl1, acc, 0, 0, 0);
        acc = __builtin_amdgcn_mfma_f32_16x16x32_bf16(b0l, wh0, acc, 0, 0, 0);
        acc = __builtin_amdgcn_mfma_f32_16x16x32_bf16(b1l, wh1, acc, 0, 0, 0);
        float mA = -FLT_MAX, mB = -FLT_MAX;
        #pragma unroll
        for (int r = 0; r < 4; r++){
          int rw = 4*ag + r;
          float v = acc[r];
          bool inA = (rw < bnd);
          mA = inA ? fmaxf(mA, v) : mA;
          mB = inA ? mB : fmaxf(mB, v);
        }
        mA = fmaxf(mA, __shfl_xor(mA, 16));
        mA = fmaxf(mA, __shfl_xor(mA, 32));
        mB = fmaxf(mB, __shfl_xor(mB, 16));
        mB = fmaxf(mB, __shfl_xor(mB, 32));
        if (ag == 0){
          atomicMax(&mxp2[nA][nt*16 + c16], mono32(mA));
          if (hasB) atomicMax(&mxp2[nA+1][nt*16 + c16], mono32(mB));
        }
      }
    }
  }
  __syncthreads();
  for (int s = tid; s < 512; s += 256){
    int nl = s >> 6, c = s & 63;
    unsigned int u = mxp2[nl][c];
    unsigned int bts = (u & 0x80000000u) ? (u ^ 0x80000000u) : ~u;
    x1[(size_t)(blockIdx.x*8 + nl)*64 + c] = __uint_as_float(bts) + inb[IN_B3 + c];
  }
}

// ---------------- kNN2 phase A: MFMA distance tiles + u32 value top-20 ----------------
__global__ __launch_bounds__(256, 4) void k_knn2a(const float* x1, unsigned* part){
  __shared__ __align__(16) char sm2[35584];
  unsigned short* Ch = (unsigned short*)sm2;            // [64][72] bf16-hi 9216B
  unsigned short* Cl = (unsigned short*)(sm2 + 9216);   // [64][72] bf16-lo 9216B
  float* Dd  = (float*)(sm2 + 18432);                   // [64*65] dist tile 16640B
  float* sqc = (float*)(sm2 + 35072);                   // [64]
  float* sqq = (float*)(sm2 + 35328);                   // [64]
  unsigned* mrgA = (unsigned*)sm2;                      // overlay (post-scan)
  unsigned* mrgB = (unsigned*)(sm2 + 5376);
  int bb   = blockIdx.x >> 5;
  int qg   = (blockIdx.x >> 1) & 15;
  int half = blockIdx.x & 1;
  int tid = threadIdx.x;
  int q_l = tid & 63;
  int wv = tid >> 6;                 // wave index == selection slot
  int lane = tid & 63;
  int c16 = lane & 15, ag = lane >> 4, kb0 = ag*8;
  int qbase = bb*1024 + qg*64;
  // A-fragments: wave wv owns query rows wv*16..+16; lane row = c16
  bf16x8 qh0, qh1, ql0, ql1;
  {
    const float* qr = x1 + (size_t)(qbase + wv*16 + c16)*64;
    f32x4 v0 = *(const f32x4*)(qr + kb0);
    f32x4 v1 = *(const f32x4*)(qr + kb0 + 4);
    f32x4 v2 = *(const f32x4*)(qr + 32 + kb0);
    f32x4 v3 = *(const f32x4*)(qr + 36 + kb0);
    #pragma unroll
    for (int e = 0; e < 4; e++){
      unsigned short hh, ll;
      bfsplit(v0[e], hh, ll); qh0[e] = (short)hh; ql0[e] = (short)ll;
      bfsplit(v1[e], hh, ll); qh0[4+e] = (short)hh; ql0[4+e] = (short)ll;
      bfsplit(v2[e], hh, ll); qh1[e] = (short)hh; ql1[e] = (short)ll;
      bfsplit(v3[e], hh, ll); qh1[4+e] = (short)hh; ql1[4+e] = (short)ll;
    }
  }
  if (tid < 64){
    const float* xr = x1 + (size_t)(qbase + tid)*64;
    float s = 0.f;
    #pragma unroll
    for (int d4 = 0; d4 < 16; d4++){
      f32x4 v = *(const f32x4*)(xr + d4*4);
      s += v[0]*v[0] + v[1]*v[1] + v[2]*v[2] + v[3]*v[3];
    }
    sqq[tid] = s;
  }
  REP20(KDECLU)
  for (int ch = 0; ch < 8; ch++){
    int c0 = half*512 + ch*64;
    __syncthreads();                 // prev D consumed (and sqq ready on ch=0)
    // stage C chunk pre-split: 2048 float-pairs / 256 threads
    for (int pp = tid; pp < 2048; pp += 256){
      int row = pp >> 5, cp = pp & 31;
      const float* src = x1 + (size_t)(bb*1024 + c0 + row)*64 + cp*2;
      float v0 = src[0], v1 = src[1];
      unsigned short h0, l0, h1, l1;
      bfsplit(v0, h0, l0); bfsplit(v1, h1, l1);
      ((unsigned int*)Ch)[row*36 + cp] = (unsigned int)h0 | ((unsigned int)h1 << 16);
      ((unsigned int*)Cl)[row*36 + cp] = (unsigned int)l0 | ((unsigned int)l1 << 16);
    }
    __syncthreads();
    if (tid < 64){                   // sqc from exact split reconstruction
      float s = 0.f;
      for (int dw = 0; dw < 32; dw++){
        unsigned int hw = ((unsigned int*)Ch)[tid*36 + dw];
        unsigned int lw = ((unsigned int*)Cl)[tid*36 + dw];
        float a0 = __uint_as_float(hw << 16) + __uint_as_float(lw << 16);
        float a1 = __uint_as_float(hw & 0xFFFF0000u) + __uint_as_float(lw & 0xFFFF0000u);
        s += a0*a0 + a1*a1;
      }
      sqc[tid] = s;
    }
    __syncthreads();
    // MFMA phase: wave wv computes D rows [wv*16, wv*16+16) x 64 cands
    #pragma unroll
    for (int nt = 0; nt < 4; nt++){
      bf16x8 bh0 = *(const bf16x8*)(Ch + (nt*16 + c16)*72 + kb0);
      bf16x8 bh1 = *(const bf16x8*)(Ch + (nt*16 + c16)*72 + 32 + kb0);
      bf16x8 bl0 = *(const bf16x8*)(Cl + (nt*16 + c16)*72 + kb0);
      bf16x8 bl1 = *(const bf16x8*)(Cl + (nt*16 + c16)*72 + 32 + kb0);
      f32x4 p0 = {0.f,0.f,0.f,0.f}, p1 = {0.f,0.f,0.f,0.f}, p2 = {0.f,0.f,0.f,0.f};
      p0 = __builtin_amdgcn_mfma_f32_16x16x32_bf16(qh0, bh0, p0, 0, 0, 0);
      p0 = __builtin_amdgcn_mfma_f32_16x16x32_bf16(qh1, bh1, p0, 0, 0, 0);
      p1 = __builtin_amdgcn_mfma_f32_16x16x32_bf16(qh0, bl0, p1, 0, 0, 0);
      p1 = __builtin_amdgcn_mfma_f32_16x16x32_bf16(qh1, bl1, p1, 0, 0, 0);
      p2 = __builtin_amdgcn_mfma_f32_16x16x32_bf16(ql0, bh0, p2, 0, 0, 0);
      p2 = __builtin_amdgcn_mfma_f32_16x16x32_bf16(ql1, bh1, p2, 0, 0, 0);
      #pragma unroll
      for (int r = 0; r < 4; r++){
        int qrow = wv*16 + 4*ag + r;
        Dd[qrow*65 + nt*16 + c16] =
            qdist(sqq[qrow], sqc[nt*16 + c16], p0[r], p1[r], p2[r]);
      }
    }
    __syncthreads();
    // selection: lane = query q_l, wave = candidate slot (c = 4u+wv)
    for (int u = 0; u < 16; u += 2){
      int cA = 4*u + wv, cB = 4*(u+1) + wv;
      float dA = Dd[q_l*65 + cA];
      float dB = Dd[q_l*65 + cB];
      INS_U32(mono32(dA));
      INS_U32(mono32(dB));
    }
  }
  __syncthreads();                   // scan arrays dead from here (union!)
  if (wv == 1){ REP20(KPUBU_A) }
  if (wv == 3){ REP20(KPUBU_B) }
  __syncthreads();
  if ((wv & 1) == 0){
    const unsigned* src = (wv == 0) ? &mrgA[q_l*21] : &mrgB[q_l*21];
    for (int p = 0; p < KNN; p++){
      unsigned kv = src[p];
      if (kv > uk19) break;
      INS_U32(kv);
    }
  }
  __syncthreads();
  if (wv == 2){ REP20(KPUBU_B) }
  __syncthreads();
  if (wv == 0){
    const unsigned* src = &mrgB[q_l*21];
    for (int p = 0; p < KNN; p++){
      unsigned kv = src[p];
      if (kv > uk19) break;
      INS_U32(kv);
    }
    int gi = qbase + q_l;
    unsigned* gpart = part + (size_t)(gi*2 + half)*KNN;
    REP20(KSTGU)
  }
}

// ---------------- kNN2 phase B: margin-collect (key,idx) + exact sel20 ----------------
__global__ __launch_bounds__(256) void k_knn2b(const float* x1, const unsigned* kthr,
                                               int* idx2){
  __shared__ __align__(16) char sm2[35584];
  unsigned short* Ch = (unsigned short*)sm2;
  unsigned short* Cl = (unsigned short*)(sm2 + 9216);
  float* Dd  = (float*)(sm2 + 18432);
  float* sqc = (float*)(sm2 + 35072);
  float* sqq = (float*)(sm2 + 35328);
  __shared__ unsigned cnt[64];
  __shared__ unsigned keyl[64][33];          // padded: avoid stride-32 banks
  __shared__ int      idxl[64][33];
  int bb = blockIdx.x >> 4, qg = blockIdx.x & 15;
  int tid = threadIdx.x;
  int q_l = tid & 63;
  int wv = tid >> 6;
  int lane = tid & 63;
  int c16 = lane & 15, ag = lane >> 4, kb0 = ag*8;
  int qbase = bb*1024 + qg*64;
  bf16x8 qh0, qh1, ql0, ql1;
  {
    const float* qr = x1 + (size_t)(qbase + wv*16 + c16)*64;
    f32x4 v0 = *(const f32x4*)(qr + kb0);
    f32x4 v1 = *(const f32x4*)(qr + kb0 + 4);
    f32x4 v2 = *(const f32x4*)(qr + 32 + kb0);
    f32x4 v3 = *(const f32x4*)(qr + 36 + kb0);
    #pragma unroll
    for (int e = 0; e < 4; e++){
      unsigned short hh, ll;
      bfsplit(v0[e], hh, ll); qh0[e] = (short)hh; ql0[e] = (short)ll;
      bfsplit(v1[e], hh, ll); qh0[4+e] = (short)hh; ql0[4+e] = (short)ll;
      bfsplit(v2[e], hh, ll); qh1[e] = (short)hh; ql1[e] = (short)ll;
      bfsplit(v3[e], hh, ll); qh1[4+e] = (short)hh; ql1[4+e] = (short)ll;
    }
  }
  if (tid < 64){
    const float* xr = x1 + (size_t)(qbase + tid)*64;
    float s = 0.f;
    #pragma unroll
    for (int d4 = 0; d4 < 16; d4++){
      f32x4 v = *(const f32x4*)(xr + d4*4);
      s += v[0]*v[0] + v[1]*v[1] + v[2]*v[2] + v[3]*v[3];
    }
    sqq[tid] = s;
    cnt[tid] = 0u;
  }
  unsigned kt = kthr[qbase + q_l];
  unsigned ktin = kt + 2048u; if (ktin < kt) ktin = 0xFFFFFFFFu;   // margin
  for (int ch = 0; ch < 16; ch++){
    int c0 = ch*64;
    __syncthreads();
    for (int pp = tid; pp < 2048; pp += 256){
      int row = pp >> 5, cp = pp & 31;
      const float* src = x1 + (size_t)(bb*1024 + c0 + row)*64 + cp*2;
      float v0 = src[0], v1 = src[1];
      unsigned short h0, l0, h1, l1;
      bfsplit(v0, h0, l0); bfsplit(v1, h1, l1);
      ((unsigned int*)Ch)[row*36 + cp] = (unsigned int)h0 | ((unsigned int)h1 << 16);
      ((unsigned int*)Cl)[row*36 + cp] = (unsigned int)l0 | ((unsigned int)l1 << 16);
    }
    __syncthreads();
    if (tid < 64){
      float s = 0.f;
      for (int dw = 0; dw < 32; dw++){
        unsigned int hw = ((unsigned int*)Ch)[tid*36 + dw];
        unsigned int lw = ((unsigned int*)Cl)[tid*36 + dw];
        float a0 = __uint_as_float(hw << 16) + __uint_as_float(lw << 16);
        float a1 = __uint_as_float(hw & 0xFFFF0000u) + __uint_as_float(lw & 0xFFFF0000u);
        s += a0*a0 + a1*a1;
      }
      sqc[tid] = s;
    }
    __syncthreads();
    #pragma unroll
    for (int nt = 0; nt < 4; nt++){
      bf16x8 bh0 = *(const bf16x8*)(Ch + (nt*16 + c16)*72 + kb0);
      bf16x8 bh1 = *(const bf16x8*)(Ch + (nt*16 + c16)*72 + 32 + kb0);
      bf16x8 bl0 = *(const bf16x8*)(Cl + (nt*16 + c16)*72 + kb0);
      bf16x8 bl1 = *(const bf16x8*)(Cl + (nt*16 + c16)*72 + 32 + kb0);
      f32x4 p0 = {0.f,0.f,0.f,0.f}, p1 = {0.f,0.f,0.f,0.f}, p2 = {0.f,0.f,0.f,0.f};
      p0 = __builtin_amdgcn_mfma_f32_16x16x32_bf16(qh0, bh0, p0, 0, 0, 0);
      p0 = __builtin_amdgcn_mfma_f32_16x16x32_bf16(qh1, bh1, p0, 0, 0, 0);
      p1 = __builtin_amdgcn_mfma_f32_16x16x32_bf16(qh0, bl0, p1, 0, 0, 0);
      p1 = __builtin_amdgcn_mfma_f32_16x16x32_bf16(qh1, bl1, p1, 0, 0, 0);
      p2 = __builtin_amdgcn_mfma_f32_16x16x32_bf16(ql0, bh0, p2, 0, 0, 0);
      p2 = __builtin_amdgcn_mfma_f32_16x16x32_bf16(ql1, bh1, p2, 0, 0, 0);
      #pragma unroll
      for (int r = 0; r < 4; r++){
        int qrow = wv*16 + 4*ag + r;
        Dd[qrow*65 + nt*16 + c16] =
            qdist(sqq[qrow], sqc[nt*16 + c16], p0[r], p1[r], p2[r]);
      }
    }
    __syncthreads();
    for (int u = 0; u < 16; u++){
      int c = 4*u + wv;
      unsigned k = mono32(Dd[q_l*65 + c]);
      if (k <= ktin){
        unsigned p = atomicAdd(&cnt[q_l], 1u);
        if (p < 32u){ keyl[q_l][p] = k; idxl[q_l][p] = c0 + c; }
      }
    }
  }
  __syncthreads();
  if (tid < 64){
    int n = (int)umin_(cnt[tid], 32u);
    int* optr = idx2 + (size_t)(qbase + tid)*KNN;
    sel20(&keyl[tid][0], &idxl[tid][0], n, optr);
  }
}

// ---------------- fast path: B2H = x1 @ Wbot[:, q-half] ----------------
__global__ __launch_bounds__(256) void k_B2h(const float* x1, const float* inb,
                                             int q, float* B2H){
  __shared__ __align__(16) float Wbh[4096];
  __shared__ __align__(16) float xsh[1024];
  int tid = threadIdx.x;
  const float* Wb = inb + IN_WBUF + WB_WBOT;
  for (int t = tid; t < 4096; t += 256){
    int r = t >> 6, cl = t & 63;
    Wbh[t] = Wb[r*128 + q*64 + cl];
  }
  int node0 = blockIdx.x * 16;
  for (int t = tid; t < 1024; t += 256) xsh[t] = x1[node0*64 + t];
  __syncthreads();
  int n_l = tid >> 4, cg = tid & 15;
  const float* xr = xsh + n_l*64;
  float4 acc = make_float4(0.f,0.f,0.f,0.f);
  #pragma unroll 8
  for (int d = 0; d < 64; d++){
    float v = xr[d];
    float4 w = *(const float4*)(Wbh + d*64 + cg*4);
    acc.x += v*w.x; acc.y += v*w.y; acc.z += v*w.z; acc.w += v*w.w;
  }
  *(float4*)(B2H + (node0 + n_l)*64 + cg*4) = acc;
}

// ---------------- fast path: x2 half = (x1_i@Wd + bc2) + max_j B2H[j] ----------------
__global__ __launch_bounds__(256) void k_x2h(const float* x1, const float* B2H,
                                             const float* inb, const int* idx2,
                                             int q, float* x2){
  __shared__ __align__(16) float Wdh[4096];
  __shared__ __align__(16) float xsh[256];
  int tid = threadIdx.x;
  const float* Wd = inb + IN_WBUF + WB_WD;
  for (int t = tid; t < 4096; t += 256){
    int r = t >> 6, cl = t & 63;
    Wdh[t] = Wd[r*128 + q*64 + cl];
  }
  int node0 = blockIdx.x * 4;
  xsh[tid] = x1[node0*64 + tid];
  __syncthreads();
  int n_l = tid >> 6, cl = tid & 63;
  int i = node0 + n_l;
  int b = i >> 10;
  const float* xr = xsh + n_l*64;
  float acc = inb[IN_BC2 + q*64 + cl];
  #pragma unroll 8
  for (int d = 0; d < 64; d++) acc += xr[d]*Wdh[d*64 + cl];
  float m = -FLT_MAX;
  for (int kk = 0; kk < KNN; kk++){
    int j = idx2[i*KNN + kk];
    m = fmaxf(m, B2H[((b<<10)+j)*64 + cl]);
  }
  x2[i*128 + q*64 + cl] = acc + m;
}

// ---------------- slow fallback: x2 direct, LDS-staged, no B2H buffer ----------------
__global__ __launch_bounds__(256) void k_x2d(const float* x1, const float* inb,
                                             const int* idx2, float* x2){
  __shared__ __align__(16) float Wdh[4096], Wbh[4096];
  __shared__ __align__(16) float xis[1024], xjs[1024];
  int tid = threadIdx.x;
  int q = blockIdx.x & 1;
  int node0 = (blockIdx.x >> 1) * 16;
  const float* Wd = inb + IN_WBUF + WB_WD;
  const float* Wb = inb + IN_WBUF + WB_WBOT;
  for (int t = tid; t < 4096; t += 256){
    int r = t >> 6, cl = t & 63;
    Wdh[t] = Wd[r*128 + q*64 + cl];
    Wbh[t] = Wb[r*128 + q*64 + cl];
  }
  for (int t = tid; t < 1024; t += 256) xis[t] = x1[node0*64 + t];
  __syncthreads();
  int n_l = tid >> 4, cg = tid & 15;
  int i = node0 + n_l, b = i >> 10;
  const float* xr = xis + n_l*64;
  float4 af = make_float4(inb[IN_BC2 + q*64 + cg*4],   inb[IN_BC2 + q*64 + cg*4+1],
                          inb[IN_BC2 + q*64 + cg*4+2], inb[IN_BC2 + q*64 + cg*4+3]);
  #pragma unroll 8
  for (int d = 0; d < 64; d++){
    float v = xr[d];
    float4 w = *(const float4*)(Wdh + d*64 + cg*4);
    af.x += v*w.x; af.y += v*w.y; af.z += v*w.z; af.w += v*w.w;
  }
  float4 mx = make_float4(-FLT_MAX,-FLT_MAX,-FLT_MAX,-FLT_MAX);
  for (int kk = 0; kk < KNN; kk++){
    __syncthreads();
    for (int t = tid; t < 1024; t += 256){
      int nn = t >> 6, r = t & 63;
      int jj = idx2[(node0+nn)*KNN + kk];
      xjs[t] = x1[((((node0+nn) >> 10) << 10) + jj)*64 + r];
    }
    __syncthreads();
    const float* xj = xjs + n_l*64;
    float4 acc = make_float4(0.f,0.f,0.f,0.f);
    #pragma unroll 8
    for (int d = 0; d < 64; d++){
      float v = xj[d];
      float4 w = *(const float4*)(Wbh + d*64 + cg*4);
      acc.x += v*w.x; acc.y += v*w.y; acc.z += v*w.z; acc.w += v*w.w;
    }
    mx.x = fmaxf(mx.x, acc.x); mx.y = fmaxf(mx.y, acc.y);
    mx.z = fmaxf(mx.z, acc.z); mx.w = fmaxf(mx.w, acc.w);
  }
  *(float4*)(x2 + i*128 + q*64 + cg*4) =
      make_float4(af.x+mx.x, af.y+mx.y, af.z+mx.z, af.w+mx.w);
}

// ---------------- lin (192->1024) via MFMA + max over node-quarter ----------------
__global__ __launch_bounds__(512, 2) void k_linpoolm(const float* x1, const float* x2,
    const float* inb, float* pool4){
  __shared__ __align__(16) float F[16*196];         // 12544B
  int tid = threadIdx.x;
  int b = blockIdx.x >> 4, cq = (blockIdx.x >> 2) & 3, nh = blockIdx.x & 3;
  int lane = tid & 63, wv = tid >> 6;
  int c16 = lane & 15, ag = lane >> 4;
  const float* Wl = inb + IN_WBUF + WB_WL;
  // B-fragments once per block
  bf16x8 w_h[2][6], w_l[2][6];
  #pragma unroll
  for (int nt = 0; nt < 2; nt++){
    int col = cq*256 + (wv*2+nt)*16 + c16;
    #pragma unroll
    for (int ks = 0; ks < 6; ks++){
      bf16x8 h8, l8;
      #pragma unroll
      for (int e = 0; e < 8; e++){
        unsigned short hh, ll;
        bfsplit(Wl[(ks*32 + ag*8 + e)*1024 + col], hh, ll);
        h8[e] = (short)hh; l8[e] = (short)ll;
      }
      w_h[nt][ks] = h8; w_l[nt][ks] = l8;
    }
  }
  float rmax[2] = {-FLT_MAX, -FLT_MAX};
  int n0 = b*1024 + nh*256;
  for (int chk = 0; chk < 16; chk++){
    int nb = n0 + chk*16;
    __syncthreads();
    {
      int row = tid >> 5;
      int d0 = (tid & 31)*6;
      #pragma unroll
      for (int u = 0; u < 6; u++){
        int d = d0 + u;
        F[row*196 + d] = (d < 64) ? x1[(size_t)(nb+row)*64 + d]
                                  : x2[(size_t)(nb+row)*128 + d - 64];
      }
    }
    __syncthreads();
    // A-fragments: row = c16 (node), k = ks*32 + ag*8 + e
    bf16x8 a_h[6], a_l[6];
    #pragma unroll
    for (int ks = 0; ks < 6; ks++){
      f32x4 v0 = *(const f32x4*)(F + c16*196 + ks*32 + ag*8);
      f32x4 v1 = *(const f32x4*)(F + c16*196 + ks*32 + ag*8 + 4);
      bf16x8 h8, l8;
      #pragma unroll
      for (int e = 0; e < 4; e++){
        unsigned short hh, ll;
        bfsplit(v0[e], hh, ll); h8[e] = (short)hh; l8[e] = (short)ll;
        bfsplit(v1[e], hh, ll); h8[4+e] = (short)hh; l8[4+e] = (short)ll;
      }
      a_h[ks] = h8; a_l[ks] = l8;
    }
    #pragma unroll
    for (int nt = 0; nt < 2; nt++){
      f32x4 p0 = {0.f,0.f,0.f,0.f}, p1 = {0.f,0.f,0.f,0.f}, p2 = {0.f,0.f,0.f,0.f};
      #pragma unroll
      for (int ks = 0; ks < 6; ks++){
        p0 = __builtin_amdgcn_mfma_f32_16x16x32_bf16(a_h[ks], w_h[nt][ks], p0, 0, 0, 0);
        p1 = __builtin_amdgcn_mfma_f32_16x16x32_bf16(a_h[ks], w_l[nt][ks], p1, 0, 0, 0);
        p2 = __builtin_amdgcn_mfma_f32_16x16x32_bf16(a_l[ks], w_h[nt][ks], p2, 0, 0, 0);
      }
      float m = -FLT_MAX;
      #pragma unroll
      for (int r = 0; r < 4; r++) m = fmaxf(m, p0[r] + p1[r] + p2[r]);
      m = fmaxf(m, __shfl_xor(m, 16));
      m = fmaxf(m, __shfl_xor(m, 32));
      rmax[nt] = fmaxf(rmax[nt], m);
    }
  }
  if (ag == 0){
    #pragma unroll
    for (int nt = 0; nt < 2; nt++)
      pool4[nh*32768 + b*1024 + cq*256 + (wv*2+nt)*16 + c16] = rmax[nt];
  }
}

// ================= head MLP, wave-per-column =================
__global__ __launch_bounds__(256) void k_h1(const float* pool4, const float* inb,
                                            float* s1g){
  __shared__ float pl[1024];
  int b = blockIdx.x >> 4, cg = blockIdx.x & 15;
  int tid = threadIdx.x;
  for (int t = tid; t < 1024; t += 256){
    float m = fmaxf(fmaxf(pool4[b*1024 + t],         pool4[32768 + b*1024 + t]),
                    fmaxf(pool4[65536 + b*1024 + t], pool4[98304 + b*1024 + t]));
    pl[t] = m + inb[IN_BL + t];
  }
  __syncthreads();
  int wv = tid >> 6, lane = tid & 63;
  f32x4 p0 = *(const f32x4*)(pl + lane*16);
  f32x4 p1 = *(const f32x4*)(pl + lane*16 + 4);
  f32x4 p2 = *(const f32x4*)(pl + lane*16 + 8);
  f32x4 p3 = *(const f32x4*)(pl + lane*16 + 12);
  const float* WT = inb + IN_WBUF + WB_WM1;    // [512][1024] transposed
  #pragma unroll
  for (int cc = 0; cc < 8; cc++){
    int c = cg*32 + wv*8 + cc;
    const float* wr = WT + (size_t)c*1024 + lane*16;
    f32x4 w0 = *(const f32x4*)(wr);
    f32x4 w1 = *(const f32x4*)(wr + 4);
    f32x4 w2 = *(const f32x4*)(wr + 8);
    f32x4 w3 = *(const f32x4*)(wr + 12);
    float acc = w0[0]*p0[0] + w0[1]*p0[1] + w0[2]*p0[2] + w0[3]*p0[3]
              + w1[0]*p1[0] + w1[1]*p1[1] + w1[2]*p1[2] + w1[3]*p1[3]
              + w2[0]*p2[0] + w2[1]*p2[1] + w2[2]*p2[2] + w2[3]*p2[3]
              + w3[0]*p3[0] + w3[1]*p3[1] + w3[2]*p3[2] + w3[3]*p3[3];
    acc += __shfl_xor(acc, 1);  acc += __shfl_xor(acc, 2);
    acc += __shfl_xor(acc, 4);  acc += __shfl_xor(acc, 8);
    acc += __shfl_xor(acc, 16); acc += __shfl_xor(acc, 32);
    if (lane == 0) s1g[b*512 + c] = fmaxf(acc + inb[IN_BM1 + c], 0.f);
  }
}

// k_h2: grid 256 = (b, cg of 32 cols of 256). K=512, lane slice 8.
__global__ __launch_bounds__(256) void k_h2(const float* s1g, const float* inb,
                                            float* s2g){
  __shared__ float s1[512];
  int b = blockIdx.x >> 3, cg = blockIdx.x & 7;
  int tid = threadIdx.x;
  for (int t = tid; t < 512; t += 256) s1[t] = s1g[b*512 + t];
  __syncthreads();
  int wv = tid >> 6, lane = tid & 63;
  f32x4 p0 = *(const f32x4*)(s1 + lane*8);
  f32x4 p1 = *(const f32x4*)(s1 + lane*8 + 4);
  const float* WT = inb + IN_WBUF + WB_WM2;    // [256][512] transposed
  #pragma unroll
  for (int cc = 0; cc < 8; cc++){
    int c = cg*32 + wv*8 + cc;
    const float* wr = WT + (size_t)c*512 + lane*8;
    f32x4 w0 = *(const f32x4*)(wr);
    f32x4 w1 = *(const f32x4*)(wr + 4);
    float acc = w0[0]*p0[0] + w0[1]*p0[1] + w0[2]*p0[2] + w0[3]*p0[3]
              + w1[0]*p1[0] + w1[1]*p1[1] + w1[2]*p1[2] + w1[3]*p1[3];
    acc += __shfl_xor(acc, 1);  acc += __shfl_xor(acc, 2);
    acc += __shfl_xor(acc, 4);  acc += __shfl_xor(acc, 8);
    acc += __shfl_xor(acc, 16); acc += __shfl_xor(acc, 32);
    if (lane == 0) s2g[b*256 + c] = fmaxf(acc + inb[IN_BM2 + c], 0.f);
  }
}

// k_h3: grid 32 (per batch). 40 cols, K=256, lane slice 4.
__global__ __launch_bounds__(256) void k_h3(const float* s2g, const float* inb,
                                            float* out){
  __shared__ float s2[256];
  int b = blockIdx.x;
  int tid = threadIdx.x;
  s2[tid] = s2g[b*256 + tid];
  __syncthreads();
  int wv = tid >> 6, lane = tid & 63;
  f32x4 p0 = *(const f32x4*)(s2 + lane*4);
  const float* WT = inb + IN_WBUF + WB_WM3;    // [40][256] transposed
  for (int cc = 0; cc < 10; cc++){
    int c = wv*10 + cc;
    const float* wr = WT + (size_t)c*256 + lane*4;
    f32x4 w0 = *(const f32x4*)(wr);
    float acc = w0[0]*p0[0] + w0[1]*p0[1] + w0[2]*p0[2] + w0[3]*p0[3];
    acc += __shfl_xor(acc, 1);  acc += __shfl_xor(acc, 2);
    acc += __shfl_xor(acc, 4);  acc += __shfl_xor(acc, 8);
    acc += __shfl_xor(acc, 16); acc += __shfl_xor(acc, 32);
    if (lane == 0) out[b*40 + c] = acc + inb[IN_BM3 + c];
  }
}

extern "C" void kernel_launch(void* const* d_in, const int* in_sizes, int n_in,
                              void* d_out, int out_size, void* d_ws, size_t ws_size,
                              hipStream_t stream){
  float* ws     = (float*)d_ws;
  double* stats = (double*)d_ws;
  int*   flag   = (int*)d_ws + OFF_FLAG;
  float* inb    = ws + OFF_INB;
  int*   idx    = (int*)d_ws + OFF_IDX;     // idx1 early, idx2 late
  float* x1p    = ws + OFF_X1;
  float* x2p    = ws + OFF_X2;
  float* a1     = ws + OFF_X2;              // a1/c1 alias x2 region (dead before x2 written)
  float* c1     = ws + OFF_C1;
  unsigned* part32 = (unsigned*)(ws + OFF_X2);       // phase-A value lists (5.2MB)
  unsigned* kthr   = part32 + (size_t)NB*2*KNN;      // per-query 20th value
  float* pool4  = ws + OFF_POOL;
  float* B2H    = ws + OFF_B2H;
  float* s1g    = ws + OFF_IDX;             // head acts alias idx (idx2 dead after x2)
  float* s2g    = ws + OFF_IDX + 16384;
  bool fast = ws_size >= (size_t)FAST_END * 4u;

  hipMemsetAsync(stats, 0, 256*sizeof(double), stream);
  k_sniff<<<1, 64, 0, stream>>>(d_in[0], flag);
  k_cvt<<<3859, 256, 0, stream>>>(
      d_in[0], d_in[1], d_in[2], d_in[3], d_in[4], d_in[5], d_in[6], d_in[7],
      d_in[8], d_in[9], d_in[10], d_in[11], d_in[12], d_in[13], d_in[14],
      d_in[15], d_in[16], d_in[17], d_in[18], d_in[19], d_in[20], flag, inb);
  k_knn1a<<<1024, 256, 0, stream>>>(inb, part32);   // value lists in a1 region
  k_mrg2<<<128, 256, 0, stream>>>(part32, kthr);
  k_knn1b<<<512, 256, 0, stream>>>(inb, kthr, idx); // -> idx1
  k_prep1<<<8192, 256, 0, stream>>>(inb, a1, c1);   // overwrites dead part/kthr
  k_stats1<<<640, 256, 0, stream>>>(a1, c1, idx, stats);
  k_stats2m<<<4096, 256, 0, stream>>>(a1, c1, idx, inb, stats);
  k_x1m<<<4096, 256, 0, stream>>>(a1, c1, idx, inb, stats, x1p);
  k_knn2a<<<1024, 256, 0, stream>>>(x1p, part32);   // a1/c1 dead after k_x1m
  k_mrg2<<<128, 256, 0, stream>>>(part32, kthr);
  k_knn2b<<<512, 256, 0, stream>>>(x1p, kthr, idx); // -> idx2
  if (fast){
    k_B2h<<<2048, 256, 0, stream>>>(x1p, inb, 0, B2H);
    k_x2h<<<8192, 256, 0, stream>>>(x1p, B2H, inb, idx, 0, x2p);
    k_B2h<<<2048, 256, 0, stream>>>(x1p, inb, 1, B2H);
    k_x2h<<<8192, 256, 0, stream>>>(x1p, B2H, inb, idx, 1, x2p);
  } else {
    k_x2d<<<4096, 256, 0, stream>>>(x1p, inb, idx, x2p);
  }
  k_linpoolm<<<512, 512, 0, stream>>>(x1p, x2p, inb, pool4);
  k_h1<<<512, 256, 0, stream>>>(pool4, inb, s1g);   // idx2 dead here
  k_h2<<<256, 256, 0, stream>>>(s1g, inb, s2g);
  k_h3<<<32, 256, 0, stream>>>(s2g, inb, (float*)d_out);
}

// Round 14
// 761.665 us; speedup vs baseline: 1.1560x; 1.1560x over previous
//
#include <hip/hip_runtime.h>
#include <hip/hip_bf16.h>
#include <float.h>
#include <math.h>

typedef __hip_bfloat16 bf16;
typedef unsigned long long u64;

#define BATCH 32
#define NPTS  1024
#define KNN   20
#define NB    (BATCH*NPTS)      // 32768 nodes
#define NEDGE (NB*KNN)          // 655360 edges

// ---- workspace layout (float units), ws_size-adaptive ----
#define OFF_FLAG 512u
#define OFF_INB  1024u
#define OFF_IDX  988928u          // 655360 ints (idx1 early, idx2 late; s1/s2 after x2)
#define OFF_X1   1644288u         // NB*64
#define OFF_X2   3741440u         // NB*128 ; a1 @ OFF_X2, c1 @ OFF_C1 (early)
#define OFF_C1   5838592u
#define OFF_POOL 7935744u         // pool4: 4 x 32*1024
#define SLOW_END 8066816u         // 32.3 MB
#define OFF_B2H  8066816u         // NB*64 (fast path only)
#define FAST_END 10163968u        // 40.7 MB
// kNN partial lists (u64) alias OFF_X2 (dead there at both kNN points).
// Head activations s1[32*512], s2[32*256] alias OFF_IDX (idx2 dead after x2).
// ---- layout inside inb (canonical fp32 inputs) ----
#define IN_POSF 0u
#define IN_B1   98304u
#define IN_G1   98368u
#define IN_BE1  98432u
#define IN_B2   98496u
#define IN_G2   98560u
#define IN_BE2  98624u
#define IN_B3   98688u
#define IN_BC2  98752u
#define IN_BL   98880u
#define IN_BM1  99904u
#define IN_BM2  100416u
#define IN_BM3  100672u
#define IN_W1   100736u
#define IN_WBUF 101120u
#define WB_W2   0u
#define WB_W3   4096u
#define WB_WD   8192u            // Wc2 top-bot diff [64x128]
#define WB_WBOT 16384u           // Wc2 bottom      [64x128]
#define WB_WL   24576u
#define WB_WM1  221184u          // stored TRANSPOSED [512][1024] (head wave-dots)
#define WB_WM2  745472u          // stored TRANSPOSED [256][512]
#define WB_WM3  876544u          // stored TRANSPOSED [40][256]
#define IN_TOTAL 987904u

__device__ __forceinline__ float bf2f(bf16 v){ return __bfloat162float(v); }

// monotone float->u32 map: preserves IEEE-754 total order for all finite values
__device__ __forceinline__ unsigned int mono32(float f){
  unsigned int b = __float_as_uint(f);
  return b ^ ((unsigned int)((int)b >> 31) | 0x80000000u);
}

// ======== MFMA machinery (bf16 hi/lo split, fp32-accurate) ========
typedef __attribute__((ext_vector_type(8))) short bf16x8;
typedef __attribute__((ext_vector_type(4))) float f32x4;

__device__ __forceinline__ unsigned short bfhi(float f){
  unsigned int u = __float_as_uint(f);
  u += 0x7FFFu + ((u >> 16) & 1u);      // RNE to bf16
  return (unsigned short)(u >> 16);
}
__device__ __forceinline__ void bfsplit(float f, unsigned short& h, unsigned short& l){
  h = bfhi(f);
  float fh = __uint_as_float(((unsigned int)h) << 16);
  l = bfhi(f - fh);
}

// ======== exact top-k via f64-packed keys + min/max sorted-insert ========
// Key bits = (1<<62) | (f32bits(max(d,0)) << 20) | idx -> positive doubles,
// value order == lexicographic (d, idx) == top_k semantics, globally unique.
// Insert: new_rp = min(rp, max(rp-1, k)) descending (exact multiset identity).
// Round-13 lesson: splitting into value-only phase A + recompute phase B
// re-pays the chunk staging/MFMA pipeline (the real floor) and loses ~15%;
// the f64 quarter-rate insert paid ONCE is the better trade.
#define REP20(M) M(0) M(1) M(2) M(3) M(4) M(5) M(6) M(7) M(8) M(9) \
                 M(10) M(11) M(12) M(13) M(14) M(15) M(16) M(17) M(18) M(19)
#define SH19(M) M(19,18) M(18,17) M(17,16) M(16,15) M(15,14) M(14,13) M(13,12) \
                M(12,11) M(11,10) M(10,9) M(9,8) M(8,7) M(7,6) M(6,5) M(5,4) \
                M(4,3) M(3,2) M(2,1) M(1,0)

__device__ __forceinline__ double packkey(float d, int idx){
  unsigned int b = __float_as_uint(fmaxf(d, 0.0f));
  u64 k = 0x4000000000000000ULL | ((u64)b << 20) | (unsigned int)idx;
  return __longlong_as_double((long long)k);
}

#define KDECLD(p) double rk##p = DBL_MAX;
#define KMM(p,pm) rk##p = fmin(rk##p, fmax(rk##pm, _k));
#define INS_MM(kv) do{ double _k=(kv); SH19(KMM) rk0 = fmin(rk0, _k); }while(0)

#define KPUB_A(p) mrgA[q_l*21+p] = (u64)__double_as_longlong(rk##p);
#define KPUB_B(p) mrgB[q_l*21+p] = (u64)__double_as_longlong(rk##p);
#define KSTG(p)   gpart[p] = (u64)__double_as_longlong(rk##p);
#define KLDAD(p)  double rk##p = __longlong_as_double((long long)pa[p]);
#define KOUTU(p)  optr[p] = (int)((u64)__double_as_longlong(rk##p) & 1023ULL);

// ---------------- dtype sniff (fp32 vs bf16 inputs) ----------------
__global__ void k_sniff(const void* pos_raw, int* flag){
  if (blockIdx.x == 0 && threadIdx.x == 0){
    const unsigned short* h = (const unsigned short*)pos_raw;
    int wild = 0;
    for (int k = 0; k < 16; k++){
      unsigned int bits = ((unsigned int)h[2*k]) << 16;
      float v = __uint_as_float(bits);
      float a = fabsf(v);
      if (a != 0.0f && (v != v || a > 1e10f || a < 1e-10f)) wild++;
    }
    *flag = (wild >= 4) ? 1 : 0;
  }
}

__device__ __forceinline__ float rdv(const void* p, int i, int f){
  return f ? ((const float*)p)[i] : bf2f(((const bf16*)p)[i]);
}

// ---------------- normalize ALL inputs to canonical fp32 buffer ----------------
__global__ __launch_bounds__(256) void k_cvt(
    const void* pos, const void* W1, const void* b1, const void* g1, const void* be1,
    const void* W2, const void* b2, const void* g2, const void* be2,
    const void* W3, const void* b3, const void* Wc2, const void* bc2,
    const void* Wl, const void* bl, const void* Wm1, const void* bm1,
    const void* Wm2, const void* bm2, const void* Wm3, const void* bm3,
    const int* flag, float* inb){
  int id = blockIdx.x*256 + threadIdx.x;
  if (id >= (int)IN_TOTAL) return;
  int f = *flag;
  float v;
  if      (id < 98304)  v = rdv(pos, id, f);
  else if (id < 98368)  v = rdv(b1,  id-98304, f);
  else if (id < 98432)  v = rdv(g1,  id-98368, f);
  else if (id < 98496)  v = rdv(be1, id-98432, f);
  else if (id < 98560)  v = rdv(b2,  id-98496, f);
  else if (id < 98624)  v = rdv(g2,  id-98560, f);
  else if (id < 98688)  v = rdv(be2, id-98624, f);
  else if (id < 98752)  v = rdv(b3,  id-98688, f);
  else if (id < 98880)  v = rdv(bc2, id-98752, f);
  else if (id < 99904)  v = rdv(bl,  id-98880, f);
  else if (id < 100416) v = rdv(bm1, id-99904, f);
  else if (id < 100672) v = rdv(bm2, id-100416, f);
  else if (id < 100712) v = rdv(bm3, id-100672, f);
  else if (id < 100736) v = 0.0f;
  else if (id < 101120) v = rdv(W1,  id-100736, f);
  else {
    int t = id - 101120;
    if      (t < 4096)   v = rdv(W2, t, f);
    else if (t < 8192)   v = rdv(W3, t-4096, f);
    else if (t < 16384){ int u = t-8192;  v = rdv(Wc2, u, f) - rdv(Wc2, 8192+u, f); }
    else if (t < 24576){ int u = t-16384; v = rdv(Wc2, 8192+u, f); }
    else if (t < 221184) v = rdv(Wl,  t-24576, f);
    else if (t < 745472){ int u = t-221184; int c = u>>10, d = u&1023; v = rdv(Wm1, d*512+c, f); }
    else if (t < 876544){ int u = t-745472; int c = u>>9,  d = u&511;  v = rdv(Wm2, d*256+c, f); }
    else               { int u = t-876544; int c = u>>8,  d = u&255;  v = rdv(Wm3, d*40+c, f); }
  }
  inb[id] = v;
}

// ---------------- a1/c1: affine decomposition of EdgeConv1 layer1 ----------------
__global__ __launch_bounds__(256) void k_prep1(const float* inb, float* a1, float* c1){
  const float* posf = inb + IN_POSF;
  const float* W1f  = inb + IN_W1;
  const float* b1f  = inb + IN_B1;
  int id = blockIdx.x*256 + threadIdx.x;
  int bn = id >> 6, c = id & 63;
  float p0 = posf[bn*3], p1 = posf[bn*3+1], p2 = posf[bn*3+2];
  float wt0 = W1f[c],     wt1 = W1f[64+c],  wt2 = W1f[128+c];
  float wb0 = W1f[192+c], wb1 = W1f[256+c], wb2 = W1f[320+c];
  float cv = p0*wb0 + p1*wb1 + p2*wb2;
  float av = p0*(wt0-wb0) + p1*(wt1-wb1) + p2*(wt2-wb2) + b1f[c];
  a1[id] = av;  c1[id] = cv;
}

// ---------------- kNN in coordinate space (half-split, LDS-union, f64-key top-k) ----------------
__global__ __launch_bounds__(256, 2) void k_knn1(const float* inb, u64* part){
  const float* posf = inb + IN_POSF;
  __shared__ __align__(16) char sm1[21504];
  float* psx = (float*)sm1;
  float* psy = psx + 1024;
  float* psz = psy + 1024;
  float* sqs = psz + 1024;
  u64* mrgA = (u64*)sm1;              // overlay (post-scan only)
  u64* mrgB = (u64*)(sm1 + 10752);
  int bb   = blockIdx.x >> 5;
  int qg   = (blockIdx.x >> 1) & 15;
  int half = blockIdx.x & 1;
  int tid = threadIdx.x;
  int q_l = tid & 63;
  int slot = tid >> 6;
  for (int t = tid; t < 1024; t += 256){
    float x = posf[(bb*1024+t)*3], y = posf[(bb*1024+t)*3+1], z = posf[(bb*1024+t)*3+2];
    psx[t] = x; psy[t] = y; psz[t] = z; sqs[t] = x*x + y*y + z*z;
  }
  __syncthreads();
  int i_l = qg*64 + q_l;
  float xi0 = psx[i_l], xi1 = psy[i_l], xi2 = psz[i_l];
  float sqi = sqs[i_l];
  REP20(KDECLD)
  int cbase = half*512;
  for (int u = 0; u < 128; u++){
    int jj = cbase + 4*u + slot;
    float dot = xi0*psx[jj] + xi1*psy[jj] + xi2*psz[jj];
    float d = sqi + sqs[jj] - 2.0f*dot;
    INS_MM(packkey(d, jj));
  }
  __syncthreads();                    // scan arrays dead from here (union!)
  if (slot == 1){ REP20(KPUB_A) }
  if (slot == 3){ REP20(KPUB_B) }
  __syncthreads();
  if ((slot & 1) == 0){
    const u64* src = (slot == 0) ? &mrgA[q_l*21] : &mrgB[q_l*21];
    for (int p = 0; p < KNN; p++){
      double kv = __longlong_as_double((long long)src[p]);
      if (kv > rk19) break;          // sorted source: rest are worse
      INS_MM(kv);
    }
  }
  __syncthreads();
  if (slot == 2){ REP20(KPUB_B) }
  __syncthreads();
  if (slot == 0){
    const u64* src = &mrgB[q_l*21];
    for (int p = 0; p < KNN; p++){
      double kv = __longlong_as_double((long long)src[p]);
      if (kv > rk19) break;
      INS_MM(kv);
    }
    int gi = bb*1024 + i_l;
    u64* gpart = part + ((size_t)gi*2 + half)*KNN;
    REP20(KSTG)
  }
}

// ---------------- merge two sorted 20-entry half-lists per query ----------------
__global__ __launch_bounds__(256) void k_mrg(const u64* part, int* out){
  int gi = blockIdx.x*256 + threadIdx.x;    // grid 128 -> 32768 queries
  const u64* pa = part + (size_t)gi*2*KNN;
  REP20(KLDAD)                               // init from half-0 list (sorted)
  for (int p = 0; p < KNN; p++){
    double kv = __longlong_as_double((long long)pa[KNN + p]);
    if (kv > rk19) break;                    // sorted source: rest are worse
    INS_MM(kv);
  }
  int* optr = out + gi*KNN;
  REP20(KOUTU)
}

// ---------------- BN1 stats ----------------
__global__ __launch_bounds__(256) void k_stats1(const float* a1, const float* c1,
                                                const int* idx1, double* stats){
  __shared__ float rs[256], rs2[256];
  int tid = threadIdx.x, c = tid & 63, slot = tid >> 6;
  int base = blockIdx.x * 1024;
  float s = 0.f, s2 = 0.f;
  for (int t = 0; t < 256; t++){
    unsigned e = (unsigned)(base + t*4 + slot);
    int i = (int)(e / 20u);
    int b = i >> 10;
    int j = idx1[e];
    float h = a1[i*64+c] + c1[((b<<10)+j)*64 + c];
    s += h; s2 += h*h;
  }
  rs[tid] = s; rs2[tid] = s2;
  __syncthreads();
  if (slot == 0){
    double ts  = (double)rs[c]  + (double)rs[64+c]  + (double)rs[128+c]  + (double)rs[192+c];
    double ts2 = (double)rs2[c] + (double)rs2[64+c] + (double)rs2[128+c] + (double)rs2[192+c];
    atomicAdd(&stats[c], ts);
    atomicAdd(&stats[64+c], ts2);
  }
}

// ================= MFMA edge-MLP (packed edges, zero padding) =================
// Block = 8 nodes = 160 edges = 10 M-tiles of 16. Tile T covers block-local
// edges 16T..16T+15; node = row/20 via magic-mul; boundary-split max epilogue.

// ---------------- BN2 stats over P = H1 @ W2 (raw, no b2) ----------------
__global__ __launch_bounds__(256) void k_stats2m(const float* a1, const float* c1,
    const int* idx1, const float* inb, double* stats){
  __shared__ __align__(16) unsigned short W2hF[4096], W2lF[4096];
  __shared__ float sc1s[64], sh1s[64];
  __shared__ float rs[4][64], rs2[4][64];
  int tid = threadIdx.x;
  const float* wbuf = inb + IN_WBUF;
  for (int t = tid; t < 4096; t += 256){
    int nt = t >> 10, ks = (t >> 9) & 1, ln = (t >> 3) & 63, e = t & 7;
    int row = ks*32 + (ln >> 4)*8 + e;
    int col = nt*16 + (ln & 15);
    unsigned short hh, ll;
    bfsplit(wbuf[WB_W2 + row*64 + col], hh, ll);
    W2hF[t] = hh; W2lF[t] = ll;
  }
  if (tid < 64){
    int c = tid;
    const double M = (double)NEDGE;
    double m1 = stats[c]/M;
    double v1 = stats[64+c]/M - m1*m1;
    double r1 = 1.0/sqrt(v1 + 1e-5);
    double g1 = (double)inb[IN_G1 + c];
    sc1s[c] = (float)(g1*r1);
    sh1s[c] = (float)((double)inb[IN_BE1 + c] - m1*g1*r1);
  }
  __syncthreads();
  int lane = tid & 63, wv = tid >> 6;
  int c16 = lane & 15, ag = lane >> 4, kb0 = ag*8;
  float sa[4] = {0,0,0,0}, qa[4] = {0,0,0,0};
  for (int rd = 0; rd < 3; rd++){
    int T = rd*4 + wv;
    if (T < 10){
      int krow = 16*T + c16;                       // block-local edge 0..159
      int node = (krow*52429) >> 20;               // krow/20
      int nodeg = blockIdx.x*8 + node;
      int j = idx1[blockIdx.x*160 + krow];         // coalesced
      int gj = ((nodeg >> 10) << 10) + j;
      const float* ar = a1 + (size_t)nodeg*64;
      const float* cr = c1 + (size_t)gj*64;
      f32x4 av0 = *(const f32x4*)(ar + kb0);
      f32x4 av1 = *(const f32x4*)(ar + kb0 + 4);
      f32x4 av2 = *(const f32x4*)(ar + 32 + kb0);
      f32x4 av3 = *(const f32x4*)(ar + 36 + kb0);
      f32x4 cv0 = *(const f32x4*)(cr + kb0);
      f32x4 cv1 = *(const f32x4*)(cr + kb0 + 4);
      f32x4 cv2 = *(const f32x4*)(cr + 32 + kb0);
      f32x4 cv3 = *(const f32x4*)(cr + 36 + kb0);
      bf16x8 a0h, a0l, a1h_, a1l_;
      #pragma unroll
      for (int e = 0; e < 4; e++){
        unsigned short hh, ll;
        float h;
        h = fmaxf((av0[e]+cv0[e])*sc1s[kb0+e] + sh1s[kb0+e], 0.f);
        bfsplit(h, hh, ll); a0h[e] = (short)hh; a0l[e] = (short)ll;
        h = fmaxf((av1[e]+cv1[e])*sc1s[kb0+4+e] + sh1s[kb0+4+e], 0.f);
        bfsplit(h, hh, ll); a0h[4+e] = (short)hh; a0l[4+e] = (short)ll;
        h = fmaxf((av2[e]+cv2[e])*sc1s[32+kb0+e] + sh1s[32+kb0+e], 0.f);
        bfsplit(h, hh, ll); a1h_[e] = (short)hh; a1l_[e] = (short)ll;
        h = fmaxf((av3[e]+cv3[e])*sc1s[36+kb0+e] + sh1s[36+kb0+e], 0.f);
        bfsplit(h, hh, ll); a1h_[4+e] = (short)hh; a1l_[4+e] = (short)ll;
      }
      #pragma unroll
      for (int nt = 0; nt < 4; nt++){
        bf16x8 wh0 = *(const bf16x8*)(W2hF + (nt*2+0)*512 + lane*8);
        bf16x8 wh1 = *(const bf16x8*)(W2hF + (nt*2+1)*512 + lane*8);
        bf16x8 wl0 = *(const bf16x8*)(W2lF + (nt*2+0)*512 + lane*8);
        bf16x8 wl1 = *(const bf16x8*)(W2lF + (nt*2+1)*512 + lane*8);
        f32x4 acc = {0.f, 0.f, 0.f, 0.f};
        acc = __builtin_amdgcn_mfma_f32_16x16x32_bf16(a0h,  wh0, acc, 0, 0, 0);
        acc = __builtin_amdgcn_mfma_f32_16x16x32_bf16(a1h_, wh1, acc, 0, 0, 0);
        acc = __builtin_amdgcn_mfma_f32_16x16x32_bf16(a0h,  wl0, acc, 0, 0, 0);
        acc = __builtin_amdgcn_mfma_f32_16x16x32_bf16(a1h_, wl1, acc, 0, 0, 0);
        acc = __builtin_amdgcn_mfma_f32_16x16x32_bf16(a0l,  wh0, acc, 0, 0, 0);
        acc = __builtin_amdgcn_mfma_f32_16x16x32_bf16(a1l_, wh1, acc, 0, 0, 0);
        #pragma unroll
        for (int r = 0; r < 4; r++){
          float v = acc[r];                        // all rows real (no padding)
          sa[nt] += v; qa[nt] += v*v;
        }
      }
    }
  }
  #pragma unroll
  for (int nt = 0; nt < 4; nt++){
    sa[nt] += __shfl_xor(sa[nt], 16); sa[nt] += __shfl_xor(sa[nt], 32);
    qa[nt] += __shfl_xor(qa[nt], 16); qa[nt] += __shfl_xor(qa[nt], 32);
  }
  if (ag == 0){
    #pragma unroll
    for (int nt = 0; nt < 4; nt++){
      rs[wv][nt*16+c16] = sa[nt];
      rs2[wv][nt*16+c16] = qa[nt];
    }
  }
  __syncthreads();
  if (tid < 64){
    double ts = (double)rs[0][tid] + (double)rs[1][tid]
              + (double)rs[2][tid] + (double)rs[3][tid];
    double tq = (double)rs2[0][tid] + (double)rs2[1][tid]
              + (double)rs2[2][tid] + (double)rs2[3][tid];
    atomicAdd(&stats[128+tid], ts);
    atomicAdd(&stats[192+tid], tq);
  }
}

// ---------------- full MLP1 via MFMA + max over k -> x1 (packed edges) ----------------
__global__ __launch_bounds__(256, 2) void k_x1m(const float* a1, const float* c1,
    const int* idx1, const float* inb, const double* stats, float* x1){
  __shared__ __align__(16) unsigned short W2hF[4096], W2lF[4096];   // 8KB each
  __shared__ __align__(16) unsigned short W3hF[4096], W3lF[4096];
  __shared__ __align__(16) float scr[4][16*68];     // per-wave H2 relayout scratch
  __shared__ unsigned int mxp2[8][64];              // per-node channel maxes (mono32)
  __shared__ float sc1s[64], sh1s[64], sc2s[64], sh2s[64];
  int tid = threadIdx.x;
  const float* wbuf = inb + IN_WBUF;
  for (int t = tid; t < 4096; t += 256){
    int nt = t >> 10, ks = (t >> 9) & 1, ln = (t >> 3) & 63, e = t & 7;
    int row = ks*32 + (ln >> 4)*8 + e;
    int col = nt*16 + (ln & 15);
    unsigned short hh, ll;
    bfsplit(wbuf[WB_W2 + row*64 + col], hh, ll);
    W2hF[t] = hh; W2lF[t] = ll;
    bfsplit(wbuf[WB_W3 + row*64 + col], hh, ll);
    W3hF[t] = hh; W3lF[t] = ll;
  }
  for (int t = tid; t < 512; t += 256) ((unsigned int*)mxp2)[t] = 0u;
  if (tid < 64){
    int c = tid;
    const double M = (double)NEDGE;
    double m1 = stats[c]/M;
    double v1 = stats[64+c]/M - m1*m1;
    double r1 = 1.0/sqrt(v1 + 1e-5);
    double g1 = (double)inb[IN_G1 + c];
    sc1s[c] = (float)(g1*r1);
    sh1s[c] = (float)((double)inb[IN_BE1 + c] - m1*g1*r1);
    double mp = stats[128+c]/M;                  // mean of raw P (b2 cancels in BN)
    double v2 = stats[192+c]/M - mp*mp;
    double r2 = 1.0/sqrt(v2 + 1e-5);
    double g2 = (double)inb[IN_G2 + c];
    sc2s[c] = (float)(g2*r2);
    sh2s[c] = (float)((double)inb[IN_BE2 + c] - mp*g2*r2);
  }
  __syncthreads();
  int lane = tid & 63, wv = tid >> 6;
  int c16 = lane & 15, ag = lane >> 4, kb0 = ag*8;
  float scn[4], shn[4];
  #pragma unroll
  for (int nt = 0; nt < 4; nt++){
    scn[nt] = sc2s[nt*16 + c16];
    shn[nt] = sh2s[nt*16 + c16];
  }
  float* sw = &scr[wv][0];
  for (int rd = 0; rd < 3; rd++){
    int T = rd*4 + wv;
    if (T < 10){
      int krow = 16*T + c16;                       // block-local edge 0..159
      int node = (krow*52429) >> 20;               // krow/20
      int nodeg = blockIdx.x*8 + node;
      int j = idx1[blockIdx.x*160 + krow];         // coalesced
      int gj = ((nodeg >> 10) << 10) + j;
      const float* ar = a1 + (size_t)nodeg*64;
      const float* cr = c1 + (size_t)gj*64;
      f32x4 av0 = *(const f32x4*)(ar + kb0);
      f32x4 av1 = *(const f32x4*)(ar + kb0 + 4);
      f32x4 av2 = *(const f32x4*)(ar + 32 + kb0);
      f32x4 av3 = *(const f32x4*)(ar + 36 + kb0);
      f32x4 cv0 = *(const f32x4*)(cr + kb0);
      f32x4 cv1 = *(const f32x4*)(cr + kb0 + 4);
      f32x4 cv2 = *(const f32x4*)(cr + 32 + kb0);
      f32x4 cv3 = *(const f32x4*)(cr + 36 + kb0);
      bf16x8 a0h, a0l, a1h_, a1l_;
      #pragma unroll
      for (int e = 0; e < 4; e++){
        unsigned short hh, ll;
        float h;
        h = fmaxf((av0[e]+cv0[e])*sc1s[kb0+e] + sh1s[kb0+e], 0.f);
        bfsplit(h, hh, ll); a0h[e] = (short)hh; a0l[e] = (short)ll;
        h = fmaxf((av1[e]+cv1[e])*sc1s[kb0+4+e] + sh1s[kb0+4+e], 0.f);
        bfsplit(h, hh, ll); a0h[4+e] = (short)hh; a0l[4+e] = (short)ll;
        h = fmaxf((av2[e]+cv2[e])*sc1s[32+kb0+e] + sh1s[32+kb0+e], 0.f);
        bfsplit(h, hh, ll); a1h_[e] = (short)hh; a1l_[e] = (short)ll;
        h = fmaxf((av3[e]+cv3[e])*sc1s[36+kb0+e] + sh1s[36+kb0+e], 0.f);
        bfsplit(h, hh, ll); a1h_[4+e] = (short)hh; a1l_[4+e] = (short)ll;
      }
      // ---- GEMM1: P = H1 @ W2 (B-fragments streamed from LDS) ----
      f32x4 pacc[4];
      #pragma unroll
      for (int nt = 0; nt < 4; nt++){
        bf16x8 wh0 = *(const bf16x8*)(W2hF + (nt*2+0)*512 + lane*8);
        bf16x8 wh1 = *(const bf16x8*)(W2hF + (nt*2+1)*512 + lane*8);
        bf16x8 wl0 = *(const bf16x8*)(W2lF + (nt*2+0)*512 + lane*8);
        bf16x8 wl1 = *(const bf16x8*)(W2lF + (nt*2+1)*512 + lane*8);
        f32x4 acc = {0.f, 0.f, 0.f, 0.f};
        acc = __builtin_amdgcn_mfma_f32_16x16x32_bf16(a0h,  wh0, acc, 0, 0, 0);
        acc = __builtin_amdgcn_mfma_f32_16x16x32_bf16(a1h_, wh1, acc, 0, 0, 0);
        acc = __builtin_amdgcn_mfma_f32_16x16x32_bf16(a0h,  wl0, acc, 0, 0, 0);
        acc = __builtin_amdgcn_mfma_f32_16x16x32_bf16(a1h_, wl1, acc, 0, 0, 0);
        acc = __builtin_amdgcn_mfma_f32_16x16x32_bf16(a0l,  wh0, acc, 0, 0, 0);
        acc = __builtin_amdgcn_mfma_f32_16x16x32_bf16(a1l_, wh1, acc, 0, 0, 0);
        pacc[nt] = acc;
      }
      // ---- BN2 + relu, relayout D->A via per-wave LDS scratch ----
      #pragma unroll
      for (int nt = 0; nt < 4; nt++){
        #pragma unroll
        for (int r = 0; r < 4; r++){
          float v = fmaxf(pacc[nt][r]*scn[nt] + shn[nt], 0.f);
          sw[(4*ag + r)*68 + nt*16 + c16] = v;
        }
      }
      f32x4 h20 = *(const f32x4*)(sw + c16*68 + kb0);
      f32x4 h21 = *(const f32x4*)(sw + c16*68 + kb0 + 4);
      f32x4 h22 = *(const f32x4*)(sw + c16*68 + 32 + kb0);
      f32x4 h23 = *(const f32x4*)(sw + c16*68 + 36 + kb0);
      bf16x8 b0h, b0l, b1h, b1l;
      #pragma unroll
      for (int e = 0; e < 4; e++){
        unsigned short hh, ll;
        bfsplit(h20[e], hh, ll); b0h[e] = (short)hh; b0l[e] = (short)ll;
        bfsplit(h21[e], hh, ll); b0h[4+e] = (short)hh; b0l[4+e] = (short)ll;
        bfsplit(h22[e], hh, ll); b1h[e] = (short)hh; b1l[e] = (short)ll;
        bfsplit(h23[e], hh, ll); b1h[4+e] = (short)hh; b1l[4+e] = (short)ll;
      }
      // ---- GEMM2 + boundary-split masked max into per-node LDS slots ----
      int rowA = 16*T;
      int nA = (rowA*52429) >> 20;                 // first node of tile (local)
      int bnd = nA*20 + 20 - rowA;                 // rows < bnd -> node nA
      int hasB = (bnd < 16);
      #pragma unroll
      for (int nt = 0; nt < 4; nt++){
        bf16x8 wh0 = *(const bf16x8*)(W3hF + (nt*2+0)*512 + lane*8);
        bf16x8 wh1 = *(const bf16x8*)(W3hF + (nt*2+1)*512 + lane*8);
        bf16x8 wl0 = *(const bf16x8*)(W3lF + (nt*2+0)*512 + lane*8);
        bf16x8 wl1 = *(const bf16x8*)(W3lF + (nt*2+1)*512 + lane*8);
        f32x4 acc = {0.f, 0.f, 0.f, 0.f};
        acc = __builtin_amdgcn_mfma_f32_16x16x32_bf16(b0h, wh0, acc, 0, 0, 0);
        acc = __builtin_amdgcn_mfma_f32_16x16x32_bf16(b1h, wh1, acc, 0, 0, 0);
        acc = __builtin_amdgcn_mfma_f32_16x16x32_bf16(b0h, wl0, acc, 0, 0, 0);
        acc = __builtin_amdgcn_mfma_f32_16x16x32_bf16(b1h, wl1, acc, 0, 0, 0);
        acc = __builtin_amdgcn_mfma_f32_16x16x32_bf16(b0l, wh0, acc, 0, 0, 0);
        acc = __builtin_amdgcn_mfma_f32_16x16x32_bf16(b1l, wh1, acc, 0, 0, 0);
        float mA = -FLT_MAX, mB = -FLT_MAX;
        #pragma unroll
        for (int r = 0; r < 4; r++){
          int rw = 4*ag + r;
          float v = acc[r];
          bool inA = (rw < bnd);
          mA = inA ? fmaxf(mA, v) : mA;
          mB = inA ? mB : fmaxf(mB, v);
        }
        mA = fmaxf(mA, __shfl_xor(mA, 16));
        mA = fmaxf(mA, __shfl_xor(mA, 32));
        mB = fmaxf(mB, __shfl_xor(mB, 16));
        mB = fmaxf(mB, __shfl_xor(mB, 32));
        if (ag == 0){
          atomicMax(&mxp2[nA][nt*16 + c16], mono32(mA));
          if (hasB) atomicMax(&mxp2[nA+1][nt*16 + c16], mono32(mB));
        }
      }
    }
  }
  __syncthreads();
  for (int s = tid; s < 512; s += 256){
    int nl = s >> 6, c = s & 63;
    unsigned int u = mxp2[nl][c];
    unsigned int bts = (u & 0x80000000u) ? (u ^ 0x80000000u) : ~u;
    x1[(size_t)(blockIdx.x*8 + nl)*64 + c] = __uint_as_float(bts) + inb[IN_B3 + c];
  }
}

// ---------------- kNN in 64-d feature space: MFMA distance tiles + f64-key top-k ----------------
__global__ __launch_bounds__(256, 4) void k_knn2(const float* x1, u64* part){
  __shared__ __align__(16) char sm2[35584];
  unsigned short* Ch = (unsigned short*)sm2;            // [64][72] bf16-hi 9216B
  unsigned short* Cl = (unsigned short*)(sm2 + 9216);   // [64][72] bf16-lo 9216B
  float* Dd  = (float*)(sm2 + 18432);                   // [64*65] dist tile 16640B
  float* sqc = (float*)(sm2 + 35072);                   // [64]
  float* sqq = (float*)(sm2 + 35328);                   // [64]
  u64* mrgA = (u64*)sm2;                                // overlay (post-scan)
  u64* mrgB = (u64*)(sm2 + 10752);
  int bb   = blockIdx.x >> 5;
  int qg   = (blockIdx.x >> 1) & 15;
  int half = blockIdx.x & 1;
  int tid = threadIdx.x;
  int q_l = tid & 63;
  int wv = tid >> 6;                 // wave index == selection slot
  int lane = tid & 63;
  int c16 = lane & 15, ag = lane >> 4, kb0 = ag*8;
  int qbase = bb*1024 + qg*64;
  // A-fragments: wave wv owns query rows wv*16..+16; lane row = c16
  bf16x8 qh0, qh1, ql0, ql1;
  {
    const float* qr = x1 + (size_t)(qbase + wv*16 + c16)*64;
    f32x4 v0 = *(const f32x4*)(qr + kb0);
    f32x4 v1 = *(const f32x4*)(qr + kb0 + 4);
    f32x4 v2 = *(const f32x4*)(qr + 32 + kb0);
    f32x4 v3 = *(const f32x4*)(qr + 36 + kb0);
    #pragma unroll
    for (int e = 0; e < 4; e++){
      unsigned short hh, ll;
      bfsplit(v0[e], hh, ll); qh0[e] = (short)hh; ql0[e] = (short)ll;
      bfsplit(v1[e], hh, ll); qh0[4+e] = (short)hh; ql0[4+e] = (short)ll;
      bfsplit(v2[e], hh, ll); qh1[e] = (short)hh; ql1[e] = (short)ll;
      bfsplit(v3[e], hh, ll); qh1[4+e] = (short)hh; ql1[4+e] = (short)ll;
    }
  }
  if (tid < 64){
    const float* xr = x1 + (size_t)(qbase + tid)*64;
    float s = 0.f;
    #pragma unroll
    for (int d4 = 0; d4 < 16; d4++){
      f32x4 v = *(const f32x4*)(xr + d4*4);
      s += v[0]*v[0] + v[1]*v[1] + v[2]*v[2] + v[3]*v[3];
    }
    sqq[tid] = s;
  }
  REP20(KDECLD)
  for (int ch = 0; ch < 8; ch++){
    int c0 = half*512 + ch*64;
    __syncthreads();                 // prev D consumed (and sqq ready on ch=0)
    // stage C chunk pre-split: 2048 float-pairs / 256 threads
    for (int pp = tid; pp < 2048; pp += 256){
      int row = pp >> 5, cp = pp & 31;
      const float* src = x1 + (size_t)(bb*1024 + c0 + row)*64 + cp*2;
      float v0 = src[0], v1 = src[1];
      unsigned short h0, l0, h1, l1;
      bfsplit(v0, h0, l0); bfsplit(v1, h1, l1);
      ((unsigned int*)Ch)[row*36 + cp] = (unsigned int)h0 | ((unsigned int)h1 << 16);
      ((unsigned int*)Cl)[row*36 + cp] = (unsigned int)l0 | ((unsigned int)l1 << 16);
    }
    __syncthreads();
    if (tid < 64){                   // sqc from exact split reconstruction
      float s = 0.f;
      for (int dw = 0; dw < 32; dw++){
        unsigned int hw = ((unsigned int*)Ch)[tid*36 + dw];
        unsigned int lw = ((unsigned int*)Cl)[tid*36 + dw];
        float a0 = __uint_as_float(hw << 16) + __uint_as_float(lw << 16);
        float a1 = __uint_as_float(hw & 0xFFFF0000u) + __uint_as_float(lw & 0xFFFF0000u);
        s += a0*a0 + a1*a1;
      }
      sqc[tid] = s;
    }
    __syncthreads();
    // MFMA phase: wave wv computes D rows [wv*16, wv*16+16) x 64 cands
    #pragma unroll
    for (int nt = 0; nt < 4; nt++){
      bf16x8 bh0 = *(const bf16x8*)(Ch + (nt*16 + c16)*72 + kb0);
      bf16x8 bh1 = *(const bf16x8*)(Ch + (nt*16 + c16)*72 + 32 + kb0);
      bf16x8 bl0 = *(const bf16x8*)(Cl + (nt*16 + c16)*72 + kb0);
      bf16x8 bl1 = *(const bf16x8*)(Cl + (nt*16 + c16)*72 + 32 + kb0);
      f32x4 p0 = {0.f,0.f,0.f,0.f}, p1 = {0.f,0.f,0.f,0.f}, p2 = {0.f,0.f,0.f,0.f};
      p0 = __builtin_amdgcn_mfma_f32_16x16x32_bf16(qh0, bh0, p0, 0, 0, 0);
      p0 = __builtin_amdgcn_mfma_f32_16x16x32_bf16(qh1, bh1, p0, 0, 0, 0);
      p1 = __builtin_amdgcn_mfma_f32_16x16x32_bf16(qh0, bl0, p1, 0, 0, 0);
      p1 = __builtin_amdgcn_mfma_f32_16x16x32_bf16(qh1, bl1, p1, 0, 0, 0);
      p2 = __builtin_amdgcn_mfma_f32_16x16x32_bf16(ql0, bh0, p2, 0, 0, 0);
      p2 = __builtin_amdgcn_mfma_f32_16x16x32_bf16(ql1, bh1, p2, 0, 0, 0);
      #pragma unroll
      for (int r = 0; r < 4; r++){
        int qrow = wv*16 + 4*ag + r;
        float d = sqq[qrow] + sqc[nt*16 + c16] - 2.0f*(p0[r] + p1[r] + p2[r]);
        Dd[qrow*65 + nt*16 + c16] = d;
      }
    }
    __syncthreads();
    // selection: lane = query q_l, wave = candidate slot (c = 4u+wv)
    for (int u = 0; u < 16; u += 2){
      int cA = 4*u + wv, cB = 4*(u+1) + wv;
      float dA = Dd[q_l*65 + cA];
      float dB = Dd[q_l*65 + cB];
      INS_MM(packkey(dA, c0 + cA));
      INS_MM(packkey(dB, c0 + cB));
    }
  }
  __syncthreads();                   // scan arrays dead from here (union!)
  if (wv == 1){ REP20(KPUB_A) }
  if (wv == 3){ REP20(KPUB_B) }
  __syncthreads();
  if ((wv & 1) == 0){
    const u64* src = (wv == 0) ? &mrgA[q_l*21] : &mrgB[q_l*21];
    for (int p = 0; p < KNN; p++){
      double kv = __longlong_as_double((long long)src[p]);
      if (kv > rk19) break;
      INS_MM(kv);
    }
  }
  __syncthreads();
  if (wv == 2){ REP20(KPUB_B) }
  __syncthreads();
  if (wv == 0){
    const u64* src = &mrgB[q_l*21];
    for (int p = 0; p < KNN; p++){
      double kv = __longlong_as_double((long long)src[p]);
      if (kv > rk19) break;
      INS_MM(kv);
    }
    int gi = qbase + q_l;
    u64* gpart = part + ((size_t)gi*2 + half)*KNN;
    REP20(KSTG)
  }
}

// ---------------- fast path: B2H = x1 @ Wbot[:, q-half] ----------------
__global__ __launch_bounds__(256) void k_B2h(const float* x1, const float* inb,
                                             int q, float* B2H){
  __shared__ __align__(16) float Wbh[4096];
  __shared__ __align__(16) float xsh[1024];
  int tid = threadIdx.x;
  const float* Wb = inb + IN_WBUF + WB_WBOT;
  for (int t = tid; t < 4096; t += 256){
    int r = t >> 6, cl = t & 63;
    Wbh[t] = Wb[r*128 + q*64 + cl];
  }
  int node0 = blockIdx.x * 16;
  for (int t = tid; t < 1024; t += 256) xsh[t] = x1[node0*64 + t];
  __syncthreads();
  int n_l = tid >> 4, cg = tid & 15;
  const float* xr = xsh + n_l*64;
  float4 acc = make_float4(0.f,0.f,0.f,0.f);
  #pragma unroll 8
  for (int d = 0; d < 64; d++){
    float v = xr[d];
    float4 w = *(const float4*)(Wbh + d*64 + cg*4);
    acc.x += v*w.x; acc.y += v*w.y; acc.z += v*w.z; acc.w += v*w.w;
  }
  *(float4*)(B2H + (node0 + n_l)*64 + cg*4) = acc;
}

// ---------------- fast path: x2 half = (x1_i@Wd + bc2) + max_j B2H[j] ----------------
__global__ __launch_bounds__(256) void k_x2h(const float* x1, const float* B2H,
                                             const float* inb, const int* idx2,
                                             int q, float* x2){
  __shared__ __align__(16) float Wdh[4096];
  __shared__ __align__(16) float xsh[256];
  int tid = threadIdx.x;
  const float* Wd = inb + IN_WBUF + WB_WD;
  for (int t = tid; t < 4096; t += 256){
    int r = t >> 6, cl = t & 63;
    Wdh[t] = Wd[r*128 + q*64 + cl];
  }
  int node0 = blockIdx.x * 4;
  xsh[tid] = x1[node0*64 + tid];
  __syncthreads();
  int n_l = tid >> 6, cl = tid & 63;
  int i = node0 + n_l;
  int b = i >> 10;
  const float* xr = xsh + n_l*64;
  float acc = inb[IN_BC2 + q*64 + cl];
  #pragma unroll 8
  for (int d = 0; d < 64; d++) acc += xr[d]*Wdh[d*64 + cl];
  float m = -FLT_MAX;
  for (int kk = 0; kk < KNN; kk++){
    int j = idx2[i*KNN + kk];
    m = fmaxf(m, B2H[((b<<10)+j)*64 + cl]);
  }
  x2[i*128 + q*64 + cl] = acc + m;
}

// ---------------- slow fallback: x2 direct, LDS-staged, no B2H buffer ----------------
__global__ __launch_bounds__(256) void k_x2d(const float* x1, const float* inb,
                                             const int* idx2, float* x2){
  __shared__ __align__(16) float Wdh[4096], Wbh[4096];
  __shared__ __align__(16) float xis[1024], xjs[1024];
  int tid = threadIdx.x;
  int q = blockIdx.x & 1;
  int node0 = (blockIdx.x >> 1) * 16;
  const float* Wd = inb + IN_WBUF + WB_WD;
  const float* Wb = inb + IN_WBUF + WB_WBOT;
  for (int t = tid; t < 4096; t += 256){
    int r = t >> 6, cl = t & 63;
    Wdh[t] = Wd[r*128 + q*64 + cl];
    Wbh[t] = Wb[r*128 + q*64 + cl];
  }
  for (int t = tid; t < 1024; t += 256) xis[t] = x1[node0*64 + t];
  __syncthreads();
  int n_l = tid >> 4, cg = tid & 15;
  int i = node0 + n_l, b = i >> 10;
  const float* xr = xis + n_l*64;
  float4 af = make_float4(inb[IN_BC2 + q*64 + cg*4],   inb[IN_BC2 + q*64 + cg*4+1],
                          inb[IN_BC2 + q*64 + cg*4+2], inb[IN_BC2 + q*64 + cg*4+3]);
  #pragma unroll 8
  for (int d = 0; d < 64; d++){
    float v = xr[d];
    float4 w = *(const float4*)(Wdh + d*64 + cg*4);
    af.x += v*w.x; af.y += v*w.y; af.z += v*w.z; af.w += v*w.w;
  }
  float4 mx = make_float4(-FLT_MAX,-FLT_MAX,-FLT_MAX,-FLT_MAX);
  for (int kk = 0; kk < KNN; kk++){
    __syncthreads();
    for (int t = tid; t < 1024; t += 256){
      int nn = t >> 6, r = t & 63;
      int jj = idx2[(node0+nn)*KNN + kk];
      xjs[t] = x1[((((node0+nn) >> 10) << 10) + jj)*64 + r];
    }
    __syncthreads();
    const float* xj = xjs + n_l*64;
    float4 acc = make_float4(0.f,0.f,0.f,0.f);
    #pragma unroll 8
    for (int d = 0; d < 64; d++){
      float v = xj[d];
      float4 w = *(const float4*)(Wbh + d*64 + cg*4);
      acc.x += v*w.x; acc.y += v*w.y; acc.z += v*w.z; acc.w += v*w.w;
    }
    mx.x = fmaxf(mx.x, acc.x); mx.y = fmaxf(mx.y, acc.y);
    mx.z = fmaxf(mx.z, acc.z); mx.w = fmaxf(mx.w, acc.w);
  }
  *(float4*)(x2 + i*128 + q*64 + cg*4) =
      make_float4(af.x+mx.x, af.y+mx.y, af.z+mx.z, af.w+mx.w);
}

// ---------------- lin (192->1024) via MFMA + max over node-quarter ----------------
__global__ __launch_bounds__(512, 2) void k_linpoolm(const float* x1, const float* x2,
    const float* inb, float* pool4){
  __shared__ __align__(16) float F[16*196];         // 12544B
  int tid = threadIdx.x;
  int b = blockIdx.x >> 4, cq = (blockIdx.x >> 2) & 3, nh = blockIdx.x & 3;
  int lane = tid & 63, wv = tid >> 6;
  int c16 = lane & 15, ag = lane >> 4;
  const float* Wl = inb + IN_WBUF + WB_WL;
  // B-fragments once per block
  bf16x8 w_h[2][6], w_l[2][6];
  #pragma unroll
  for (int nt = 0; nt < 2; nt++){
    int col = cq*256 + (wv*2+nt)*16 + c16;
    #pragma unroll
    for (int ks = 0; ks < 6; ks++){
      bf16x8 h8, l8;
      #pragma unroll
      for (int e = 0; e < 8; e++){
        unsigned short hh, ll;
        bfsplit(Wl[(ks*32 + ag*8 + e)*1024 + col], hh, ll);
        h8[e] = (short)hh; l8[e] = (short)ll;
      }
      w_h[nt][ks] = h8; w_l[nt][ks] = l8;
    }
  }
  float rmax[2] = {-FLT_MAX, -FLT_MAX};
  int n0 = b*1024 + nh*256;
  for (int chk = 0; chk < 16; chk++){
    int nb = n0 + chk*16;
    __syncthreads();
    {
      int row = tid >> 5;
      int d0 = (tid & 31)*6;
      #pragma unroll
      for (int u = 0; u < 6; u++){
        int d = d0 + u;
        F[row*196 + d] = (d < 64) ? x1[(size_t)(nb+row)*64 + d]
                                  : x2[(size_t)(nb+row)*128 + d - 64];
      }
    }
    __syncthreads();
    // A-fragments: row = c16 (node), k = ks*32 + ag*8 + e
    bf16x8 a_h[6], a_l[6];
    #pragma unroll
    for (int ks = 0; ks < 6; ks++){
      f32x4 v0 = *(const f32x4*)(F + c16*196 + ks*32 + ag*8);
      f32x4 v1 = *(const f32x4*)(F + c16*196 + ks*32 + ag*8 + 4);
      bf16x8 h8, l8;
      #pragma unroll
      for (int e = 0; e < 4; e++){
        unsigned short hh, ll;
        bfsplit(v0[e], hh, ll); h8[e] = (short)hh; l8[e] = (short)ll;
        bfsplit(v1[e], hh, ll); h8[4+e] = (short)hh; l8[4+e] = (short)ll;
      }
      a_h[ks] = h8; a_l[ks] = l8;
    }
    #pragma unroll
    for (int nt = 0; nt < 2; nt++){
      f32x4 p0 = {0.f,0.f,0.f,0.f}, p1 = {0.f,0.f,0.f,0.f}, p2 = {0.f,0.f,0.f,0.f};
      #pragma unroll
      for (int ks = 0; ks < 6; ks++){
        p0 = __builtin_amdgcn_mfma_f32_16x16x32_bf16(a_h[ks], w_h[nt][ks], p0, 0, 0, 0);
        p1 = __builtin_amdgcn_mfma_f32_16x16x32_bf16(a_h[ks], w_l[nt][ks], p1, 0, 0, 0);
        p2 = __builtin_amdgcn_mfma_f32_16x16x32_bf16(a_l[ks], w_h[nt][ks], p2, 0, 0, 0);
      }
      float m = -FLT_MAX;
      #pragma unroll
      for (int r = 0; r < 4; r++) m = fmaxf(m, p0[r] + p1[r] + p2[r]);
      m = fmaxf(m, __shfl_xor(m, 16));
      m = fmaxf(m, __shfl_xor(m, 32));
      rmax[nt] = fmaxf(rmax[nt], m);
    }
  }
  if (ag == 0){
    #pragma unroll
    for (int nt = 0; nt < 2; nt++)
      pool4[nh*32768 + b*1024 + cq*256 + (wv*2+nt)*16 + c16] = rmax[nt];
  }
}

// ================= head MLP, wave-per-column =================
__global__ __launch_bounds__(256) void k_h1(const float* pool4, const float* inb,
                                            float* s1g){
  __shared__ float pl[1024];
  int b = blockIdx.x >> 4, cg = blockIdx.x & 15;
  int tid = threadIdx.x;
  for (int t = tid; t < 1024; t += 256){
    float m = fmaxf(fmaxf(pool4[b*1024 + t],         pool4[32768 + b*1024 + t]),
                    fmaxf(pool4[65536 + b*1024 + t], pool4[98304 + b*1024 + t]));
    pl[t] = m + inb[IN_BL + t];
  }
  __syncthreads();
  int wv = tid >> 6, lane = tid & 63;
  f32x4 p0 = *(const f32x4*)(pl + lane*16);
  f32x4 p1 = *(const f32x4*)(pl + lane*16 + 4);
  f32x4 p2 = *(const f32x4*)(pl + lane*16 + 8);
  f32x4 p3 = *(const f32x4*)(pl + lane*16 + 12);
  const float* WT = inb + IN_WBUF + WB_WM1;    // [512][1024] transposed
  #pragma unroll
  for (int cc = 0; cc < 8; cc++){
    int c = cg*32 + wv*8 + cc;
    const float* wr = WT + (size_t)c*1024 + lane*16;
    f32x4 w0 = *(const f32x4*)(wr);
    f32x4 w1 = *(const f32x4*)(wr + 4);
    f32x4 w2 = *(const f32x4*)(wr + 8);
    f32x4 w3 = *(const f32x4*)(wr + 12);
    float acc = w0[0]*p0[0] + w0[1]*p0[1] + w0[2]*p0[2] + w0[3]*p0[3]
              + w1[0]*p1[0] + w1[1]*p1[1] + w1[2]*p1[2] + w1[3]*p1[3]
              + w2[0]*p2[0] + w2[1]*p2[1] + w2[2]*p2[2] + w2[3]*p2[3]
              + w3[0]*p3[0] + w3[1]*p3[1] + w3[2]*p3[2] + w3[3]*p3[3];
    acc += __shfl_xor(acc, 1);  acc += __shfl_xor(acc, 2);
    acc += __shfl_xor(acc, 4);  acc += __shfl_xor(acc, 8);
    acc += __shfl_xor(acc, 16); acc += __shfl_xor(acc, 32);
    if (lane == 0) s1g[b*512 + c] = fmaxf(acc + inb[IN_BM1 + c], 0.f);
  }
}

// k_h2: grid 256 = (b, cg of 32 cols of 256). K=512, lane slice 8.
__global__ __launch_bounds__(256) void k_h2(const float* s1g, const float* inb,
                                            float* s2g){
  __shared__ float s1[512];
  int b = blockIdx.x >> 3, cg = blockIdx.x & 7;
  int tid = threadIdx.x;
  for (int t = tid; t < 512; t += 256) s1[t] = s1g[b*512 + t];
  __syncthreads();
  int wv = tid >> 6, lane = tid & 63;
  f32x4 p0 = *(const f32x4*)(s1 + lane*8);
  f32x4 p1 = *(const f32x4*)(s1 + lane*8 + 4);
  const float* WT = inb + IN_WBUF + WB_WM2;    // [256][512] transposed
  #pragma unroll
  for (int cc = 0; cc < 8; cc++){
    int c = cg*32 + wv*8 + cc;
    const float* wr = WT + (size_t)c*512 + lane*8;
    f32x4 w0 = *(const f32x4*)(wr);
    f32x4 w1 = *(const f32x4*)(wr + 4);
    float acc = w0[0]*p0[0] + w0[1]*p0[1] + w0[2]*p0[2] + w0[3]*p0[3]
              + w1[0]*p1[0] + w1[1]*p1[1] + w1[2]*p1[2] + w1[3]*p1[3];
    acc += __shfl_xor(acc, 1);  acc += __shfl_xor(acc, 2);
    acc += __shfl_xor(acc, 4);  acc += __shfl_xor(acc, 8);
    acc += __shfl_xor(acc, 16); acc += __shfl_xor(acc, 32);
    if (lane == 0) s2g[b*256 + c] = fmaxf(acc + inb[IN_BM2 + c], 0.f);
  }
}

// k_h3: grid 32 (per batch). 40 cols, K=256, lane slice 4.
__global__ __launch_bounds__(256) void k_h3(const float* s2g, const float* inb,
                                            float* out){
  __shared__ float s2[256];
  int b = blockIdx.x;
  int tid = threadIdx.x;
  s2[tid] = s2g[b*256 + tid];
  __syncthreads();
  int wv = tid >> 6, lane = tid & 63;
  f32x4 p0 = *(const f32x4*)(s2 + lane*4);
  const float* WT = inb + IN_WBUF + WB_WM3;    // [40][256] transposed
  for (int cc = 0; cc < 10; cc++){
    int c = wv*10 + cc;
    const float* wr = WT + (size_t)c*256 + lane*4;
    f32x4 w0 = *(const f32x4*)(wr);
    float acc = w0[0]*p0[0] + w0[1]*p0[1] + w0[2]*p0[2] + w0[3]*p0[3];
    acc += __shfl_xor(acc, 1);  acc += __shfl_xor(acc, 2);
    acc += __shfl_xor(acc, 4);  acc += __shfl_xor(acc, 8);
    acc += __shfl_xor(acc, 16); acc += __shfl_xor(acc, 32);
    if (lane == 0) out[b*40 + c] = acc + inb[IN_BM3 + c];
  }
}

extern "C" void kernel_launch(void* const* d_in, const int* in_sizes, int n_in,
                              void* d_out, int out_size, void* d_ws, size_t ws_size,
                              hipStream_t stream){
  float* ws     = (float*)d_ws;
  double* stats = (double*)d_ws;
  int*   flag   = (int*)d_ws + OFF_FLAG;
  float* inb    = ws + OFF_INB;
  int*   idx    = (int*)d_ws + OFF_IDX;     // idx1 early, idx2 late
  float* x1p    = ws + OFF_X1;
  float* x2p    = ws + OFF_X2;
  float* a1     = ws + OFF_X2;              // a1/c1 alias x2 region (dead before x2 written)
  float* c1     = ws + OFF_C1;
  u64*   part   = (u64*)(ws + OFF_X2);      // kNN partials alias a1/c1 (see layout note)
  float* pool4  = ws + OFF_POOL;
  float* B2H    = ws + OFF_B2H;
  float* s1g    = ws + OFF_IDX;             // head acts alias idx (idx2 dead after x2)
  float* s2g    = ws + OFF_IDX + 16384;
  bool fast = ws_size >= (size_t)FAST_END * 4u;

  hipMemsetAsync(stats, 0, 256*sizeof(double), stream);
  k_sniff<<<1, 64, 0, stream>>>(d_in[0], flag);
  k_cvt<<<3859, 256, 0, stream>>>(
      d_in[0], d_in[1], d_in[2], d_in[3], d_in[4], d_in[5], d_in[6], d_in[7],
      d_in[8], d_in[9], d_in[10], d_in[11], d_in[12], d_in[13], d_in[14],
      d_in[15], d_in[16], d_in[17], d_in[18], d_in[19], d_in[20], flag, inb);
  k_knn1<<<1024, 256, 0, stream>>>(inb, part);      // partials in a1/c1 region
  k_mrg<<<128, 256, 0, stream>>>(part, idx);        // -> idx1
  k_prep1<<<8192, 256, 0, stream>>>(inb, a1, c1);   // overwrites dead partials
  k_stats1<<<640, 256, 0, stream>>>(a1, c1, idx, stats);
  k_stats2m<<<4096, 256, 0, stream>>>(a1, c1, idx, inb, stats);
  k_x1m<<<4096, 256, 0, stream>>>(a1, c1, idx, inb, stats, x1p);
  k_knn2<<<1024, 256, 0, stream>>>(x1p, part);      // a1/c1 dead after k_x1m
  k_mrg<<<128, 256, 0, stream>>>(part, idx);        // -> idx2
  if (fast){
    k_B2h<<<2048, 256, 0, stream>>>(x1p, inb, 0, B2H);
    k_x2h<<<8192, 256, 0, stream>>>(x1p, B2H, inb, idx, 0, x2p);
    k_B2h<<<2048, 256, 0, stream>>>(x1p, inb, 1, B2H);
    k_x2h<<<8192, 256, 0, stream>>>(x1p, B2H, inb, idx, 1, x2p);
  } else {
    k_x2d<<<4096, 256, 0, stream>>>(x1p, inb, idx, x2p);
  }
  k_linpoolm<<<512, 512, 0, stream>>>(x1p, x2p, inb, pool4);
  k_h1<<<512, 256, 0, stream>>>(pool4, inb, s1g);   // idx2 dead here
  k_h2<<<256, 256, 0, stream>>>(s1g, inb, s2g);
  k_h3<<<32, 256, 0, stream>>>(s2g, inb, (float*)d_out);
}